// Round 10
// baseline (433.224 us; speedup 1.0000x reference)
//
#include <hip/hip_runtime.h>
#include <hip/hip_fp16.h>
#include <math.h>

#define NN 100000
#define NE 3200000
#define FEA 67
#define HID 16
#define OUTC 2
#define KS 3
#define KH 48   /* KS*HID */
#define KO 6    /* KS*OUTC */

#define PB 512          /* partition blocks */
#define EPB 6250        /* edges per partition block (PB*EPB == NE) */
#define BINW 512        /* nodes per bin */
#define NBINS 196       /* ceil(NN/BINW) */
#define M1 (NBINS * PB) /* 100352 */
#define NSCB 98         /* scan blocks: 98*1024 == M1 exactly */
#define CSR_CAP (NE + NBINS * 7 * BINW + 64)   /* pad-to-8 CSR capacity */

#define TBM 128               /* transform1 nodes per block */
#define TNB ((NN + TBM - 1) / TBM)   /* 782 */
#define XS_STRIDE 132         /* xT row stride */
#define WT_STRIDE 68          /* wT row stride */

#define APS ((size_t)(NN + 1) * 8)   /* A/B plane stride in half2 (pad row NN) */
#define RPS ((size_t)NN * 8)         /* R plane stride in half2 */

// ---------------- partition: histogram ----------------

__global__ void k_hist(const int* __restrict__ dst, int* __restrict__ hist) {
    __shared__ int h[NBINS];
    if (threadIdx.x < NBINS) h[threadIdx.x] = 0;
    __syncthreads();
    int base = blockIdx.x * EPB;
    for (int i = threadIdx.x; i < EPB; i += 256)
        atomicAdd(&h[dst[base + i] >> 9], 1);
    __syncthreads();
    if (threadIdx.x < NBINS) hist[threadIdx.x * PB + blockIdx.x] = h[threadIdx.x];
}

// ---------------- 2-kernel exclusive scan ----------------

__global__ void k_partial(const int* __restrict__ in, int* __restrict__ partials, int n) {
    __shared__ int s[256];
    int base = blockIdx.x * 1024;
    int acc = 0;
    for (int i = threadIdx.x; i < 1024; i += 256) {
        int idx = base + i;
        if (idx < n) acc += in[idx];
    }
    s[threadIdx.x] = acc;
    __syncthreads();
    for (int off = 128; off > 0; off >>= 1) {
        if (threadIdx.x < off) s[threadIdx.x] += s[threadIdx.x + off];
        __syncthreads();
    }
    if (threadIdx.x == 0) partials[blockIdx.x] = s[0];
}

__global__ void k_downsweepF(const int* __restrict__ in, const int* __restrict__ partials,
                             int* __restrict__ out, int n) {
    __shared__ int ps[256];
    __shared__ int s[256];
    int t = threadIdx.x;
    ps[t] = (t < NSCB) ? partials[t] : 0;
    __syncthreads();
    for (int off = 1; off < 256; off <<= 1) {
        int v = (t >= off) ? ps[t - off] : 0;
        __syncthreads();
        ps[t] += v;
        __syncthreads();
    }
    int bbase = (blockIdx.x > 0) ? ps[blockIdx.x - 1] : 0;

    int base = blockIdx.x * 1024 + t * 4;
    int d0 = 0, d1 = 0, d2 = 0, d3 = 0;
    if (base + 0 < n) d0 = in[base + 0];
    if (base + 1 < n) d1 = in[base + 1];
    if (base + 2 < n) d2 = in[base + 2];
    if (base + 3 < n) d3 = in[base + 3];
    int ts = d0 + d1 + d2 + d3;
    s[t] = ts;
    __syncthreads();
    for (int off = 1; off < 256; off <<= 1) {
        int v = (t >= off) ? s[t - off] : 0;
        __syncthreads();
        s[t] += v;
        __syncthreads();
    }
    int excl = s[t] - ts + bbase;
    if (base + 0 < n) out[base + 0] = excl;
    if (base + 1 < n) out[base + 1] = excl + d0;
    if (base + 2 < n) out[base + 2] = excl + d0 + d1;
    if (base + 3 < n) out[base + 3] = excl + d0 + d1 + d2;
}

// ---------------- partition: scatter to bins ----------------

__global__ void k_pass2(const int* __restrict__ src, const int* __restrict__ dst,
                        const int* __restrict__ hist_scan, int* __restrict__ recs) {
    __shared__ int curs[NBINS];
    if (threadIdx.x < NBINS) curs[threadIdx.x] = hist_scan[threadIdx.x * PB + blockIdx.x];
    __syncthreads();
    int base = blockIdx.x * EPB;
    for (int i = threadIdx.x; i < EPB; i += 256) {
        int e = base + i;
        int s = src[e], d = dst[e];
        int pos = atomicAdd(&curs[d >> 9], 1);
        recs[pos] = s | ((d & 511) << 17);            // src:17b | dst_local:9b
    }
}

// ---------------- fused per-bin: degree + dinv + pad-8 row_start + CSR scatter ----------------

__global__ void k_degsort(const int* __restrict__ recs, const int* __restrict__ hist_scan,
                          int* __restrict__ deg, float* __restrict__ dinv,
                          int* __restrict__ row_start, int* __restrict__ csr) {
    __shared__ int cnt[BINW];
    __shared__ int scn[BINW];
    int bin = blockIdx.x, t = threadIdx.x;
    cnt[t] = 0;
    __syncthreads();
    int s0 = hist_scan[bin * PB];
    int s1 = (bin + 1 < NBINS) ? hist_scan[(bin + 1) * PB] : NE;
    for (int r = s0 + t; r < s1; r += BINW)
        atomicAdd(&cnt[((unsigned)recs[r]) >> 17], 1);
    __syncthreads();
    int c  = cnt[t];
    int c8 = (c + 7) & ~7;
    scn[t] = c8;
    __syncthreads();
    for (int off = 1; off < BINW; off <<= 1) {
        int v = (t >= off) ? scn[t - off] : 0;
        __syncthreads();
        scn[t] += v;
        __syncthreads();
    }
    int base = s0 + bin * (7 * BINW);      // pad-8 region base for this bin
    int rs   = base + scn[t] - c8;         // exclusive padded prefix
    int node = bin * BINW + t;
    if (node < NN) {
        deg[node]       = c;
        dinv[node]      = (c > 0) ? rsqrtf((float)c) : 0.f;
        row_start[node] = rs;
    }
    scn[t] = rs;                            // scatter cursor
    __syncthreads();
    for (int r = s0 + t; r < s1; r += BINW) {
        int rec = recs[r];
        int pos = atomicAdd(&scn[((unsigned)rec) >> 17], 1);
        csr[pos] = rec & 0x1FFFF;
    }
    __syncthreads();
    int e8 = rs + c8;
    for (int i = scn[t]; i < e8; ++i) csr[i] = NN;   // sentinel pads (zero row)
}

// ---------------- layer 1 dense transform: register-tiled GEMM -> per-stack planes ----------------

__global__ void k_transform1(const float* __restrict__ x, const float* __restrict__ iw,
                             const float* __restrict__ rw, const float* __restrict__ b1,
                             const float* __restrict__ dinv,
                             __half2* __restrict__ Ap, __half2* __restrict__ Bp,
                             __half2* __restrict__ Rp) {
    if (blockIdx.x == TNB) {   // zero pad row NN of each A/B plane (8 half2 per plane)
        int t = threadIdx.x;
        __half2 z = __halves2half2(__float2half(0.f), __float2half(0.f));
        if (t < 24)      Ap[(size_t)(t >> 3) * APS + (size_t)NN * 8 + (t & 7)] = z;
        else if (t < 48) Bp[(size_t)((t - 24) >> 3) * APS + (size_t)NN * 8 + ((t - 24) & 7)] = z;
        return;
    }
    __shared__ float xs[FEA * XS_STRIDE];
    __shared__ float wTs[96 * WT_STRIDE];
    __shared__ float bb[KH];
    int n0g = blockIdx.x * TBM;

    for (int idx = threadIdx.x; idx < 96 * FEA; idx += 256) {
        int j = idx / FEA, f = idx % FEA;
        float v;
        if (j < KH) v = iw[(j >> 4) * (FEA * HID) + f * HID + (j & 15)];
        else { int jr = j - KH; v = rw[(jr >> 4) * (FEA * HID) + f * HID + (jr & 15)]; }
        wTs[j * WT_STRIDE + f] = v;
    }
    if (threadIdx.x < KH) bb[threadIdx.x] = b1[threadIdx.x];
    for (int idx = threadIdx.x; idx < TBM * FEA; idx += 256) {
        int nl = idx / FEA, f = idx % FEA;
        int n = n0g + nl;
        xs[f * XS_STRIDE + nl] = (n < NN) ? x[(size_t)n * FEA + f] : 0.f;
    }
    __syncthreads();

    int tx = threadIdx.x & 31, ty = threadIdx.x >> 5;
    int nl0 = tx * 4;
    int j0  = ty * 12;
    float acc[4][12];
    #pragma unroll
    for (int p = 0; p < 12; ++p) {
        float init = (j0 >= KH) ? bb[j0 - KH + p] : 0.f;
        acc[0][p] = init; acc[1][p] = init; acc[2][p] = init; acc[3][p] = init;
    }

    #pragma unroll 4
    for (int fb = 0; fb < 16; ++fb) {
        int f0 = fb * 4;
        float4 xv0 = *(const float4*)&xs[(f0 + 0) * XS_STRIDE + nl0];
        float4 xv1 = *(const float4*)&xs[(f0 + 1) * XS_STRIDE + nl0];
        float4 xv2 = *(const float4*)&xs[(f0 + 2) * XS_STRIDE + nl0];
        float4 xv3 = *(const float4*)&xs[(f0 + 3) * XS_STRIDE + nl0];
        #pragma unroll
        for (int p = 0; p < 12; ++p) {
            float4 wv = *(const float4*)&wTs[(j0 + p) * WT_STRIDE + f0];
            acc[0][p] += xv0.x * wv.x + xv1.x * wv.y + xv2.x * wv.z + xv3.x * wv.w;
            acc[1][p] += xv0.y * wv.x + xv1.y * wv.y + xv2.y * wv.z + xv3.y * wv.w;
            acc[2][p] += xv0.z * wv.x + xv1.z * wv.y + xv2.z * wv.z + xv3.z * wv.w;
            acc[3][p] += xv0.w * wv.x + xv1.w * wv.y + xv2.w * wv.z + xv3.w * wv.w;
        }
    }
    #pragma unroll
    for (int f = 64; f < FEA; ++f) {
        float x0 = xs[f * XS_STRIDE + nl0 + 0];
        float x1 = xs[f * XS_STRIDE + nl0 + 1];
        float x2 = xs[f * XS_STRIDE + nl0 + 2];
        float x3 = xs[f * XS_STRIDE + nl0 + 3];
        #pragma unroll
        for (int p = 0; p < 12; ++p) {
            float wv = wTs[(j0 + p) * WT_STRIDE + f];
            acc[0][p] += x0 * wv; acc[1][p] += x1 * wv;
            acc[2][p] += x2 * wv; acc[3][p] += x3 * wv;
        }
    }

    if (j0 < KH) {   // A outputs: scale by dinv, plane layout
        #pragma unroll
        for (int nq = 0; nq < 4; ++nq) {
            int n = n0g + nl0 + nq;
            if (n < NN) {
                float dv = dinv[n];
                #pragma unroll
                for (int p2 = 0; p2 < 6; ++p2) {
                    int jp = j0 + 2 * p2;
                    Ap[(size_t)(jp >> 4) * APS + (size_t)n * 8 + ((jp & 15) >> 1)] =
                        __halves2half2(__float2half_rn(acc[nq][2 * p2] * dv),
                                       __float2half_rn(acc[nq][2 * p2 + 1] * dv));
                }
            }
        }
    } else {         // R outputs: plane layout (bias already in acc)
        int jr0 = j0 - KH;
        #pragma unroll
        for (int nq = 0; nq < 4; ++nq) {
            int n = n0g + nl0 + nq;
            if (n < NN) {
                #pragma unroll
                for (int p2 = 0; p2 < 6; ++p2) {
                    int jp = jr0 + 2 * p2;
                    Rp[(size_t)(jp >> 4) * RPS + (size_t)n * 8 + ((jp & 15) >> 1)] =
                        __halves2half2(__float2half_rn(acc[nq][2 * p2]),
                                       __float2half_rn(acc[nq][2 * p2 + 1]));
                }
            }
        }
    }
}

// ---------------- per-stack SpMM 16-wide: 8 edges x 8 col-lanes, L2-resident plane ----------------

template <bool FUSEW>
__global__ void k_spmm16(const __half2* __restrict__ Ak,   // plane k, row stride 8 half2
                         const __half2* __restrict__ Rk,   // plane k, row stride 8 half2
                         const int* __restrict__ row_start, const int* __restrict__ deg,
                         const float* __restrict__ dinv, const int* __restrict__ csr,
                         const float* __restrict__ w1k,    // w1 + k*256
                         __half2* __restrict__ Bk) {
    __shared__ float w1s[FUSEW ? HID * HID : 1];
    if (FUSEW) {
        if (threadIdx.x < HID * HID) w1s[threadIdx.x] = w1k[threadIdx.x];
        __syncthreads();
    }
    int node = (blockIdx.x * 256 + threadIdx.x) >> 6;   // one wave per node (grid exact)
    int lane = threadIdx.x & 63;
    int eo   = lane >> 3;           // edge offset within octet (0..7)
    int cl   = lane & 7;            // col-pair (cols 2cl, 2cl+1)
    int start = __builtin_amdgcn_readfirstlane(row_start[node]);
    int d     = __builtin_amdgcn_readfirstlane(deg[node]);
    int d8    = (d + 7) & ~7;       // csr padded with NN sentinels (zero row)
    float dv  = dinv[node];
    float2 r2 = __half22float2(Rk[(size_t)node * 8 + cl]);

    float ax = 0.f, ay = 0.f;
    for (int b = 0; b < d8; b += 64) {
        int nb  = min(64, d8 - b);              // multiple of 8
        int myc = csr[start + b + lane];        // unguarded: pad-8 CSR + slack
        int npf = nb >> 3;                      // octets (1..8)
        int p = 0;
        for (; p + 4 <= npf; p += 4) {
            int c0 = __shfl(myc, (p + 0) * 8 + eo, 64);
            int c1 = __shfl(myc, (p + 1) * 8 + eo, 64);
            int c2 = __shfl(myc, (p + 2) * 8 + eo, 64);
            int c3 = __shfl(myc, (p + 3) * 8 + eo, 64);
            float2 f0 = __half22float2(Ak[((size_t)c0 << 3) + cl]);
            float2 f1 = __half22float2(Ak[((size_t)c1 << 3) + cl]);
            float2 f2 = __half22float2(Ak[((size_t)c2 << 3) + cl]);
            float2 f3 = __half22float2(Ak[((size_t)c3 << 3) + cl]);
            ax += f0.x + f1.x; ay += f0.y + f1.y;
            ax += f2.x + f3.x; ay += f2.y + f3.y;
        }
        for (; p < npf; ++p) {
            int c = __shfl(myc, p * 8 + eo, 64);
            float2 f = __half22float2(Ak[((size_t)c << 3) + cl]);
            ax += f.x; ay += f.y;
        }
    }
    // reduce across the 8 edge-groups (lane bits 3,4,5)
    ax += __shfl_xor(ax, 8, 64);  ay += __shfl_xor(ay, 8, 64);
    ax += __shfl_xor(ax, 16, 64); ay += __shfl_xor(ay, 16, 64);
    ax += __shfl_xor(ax, 32, 64); ay += __shfl_xor(ay, 32, 64);
    float vx = fmaxf(ax * dv + r2.x, 0.f);      // post-scale dinv[dst], +root, relu
    float vy = fmaxf(ay * dv + r2.y, 0.f);

    if (FUSEW) {
        // out[p0], out[p0+1] = sum_h in[h] * w1k[h][p];  lane h2 holds cols 2h2, 2h2+1
        int p0 = 2 * cl;
        float o0 = 0.f, o1 = 0.f;
        #pragma unroll
        for (int h2 = 0; h2 < 8; ++h2) {
            float ix = __shfl(vx, h2, 64);
            float iy = __shfl(vy, h2, 64);
            o0 += ix * w1s[(2 * h2) * 16 + p0]     + iy * w1s[(2 * h2 + 1) * 16 + p0];
            o1 += ix * w1s[(2 * h2) * 16 + p0 + 1] + iy * w1s[(2 * h2 + 1) * 16 + p0 + 1];
        }
        if (eo == 0)
            Bk[(size_t)node * 8 + cl] =
                __halves2half2(__float2half_rn(o0 * dv), __float2half_rn(o1 * dv));
    } else {
        if (eo == 0)
            Bk[(size_t)node * 8 + cl] =
                __halves2half2(__float2half_rn(vx), __float2half_rn(vy));
    }
}

// ---------------- fused mean+relu+transform2 (reads L1 planes) ----------------

__global__ void k_mt2(const __half2* __restrict__ L1, const float* __restrict__ iw,
                      const float* __restrict__ rw, const float* __restrict__ b2,
                      const float* __restrict__ dinv,
                      float* __restrict__ A2, float* __restrict__ R2) {
    __shared__ float wi[KS * HID * OUTC];
    __shared__ float wr_[KS * HID * OUTC];
    __shared__ float bb[KO];
    if (threadIdx.x < KS * HID * OUTC) { wi[threadIdx.x] = iw[threadIdx.x]; wr_[threadIdx.x] = rw[threadIdx.x]; }
    if (threadIdx.x < KO) bb[threadIdx.x] = b2[threadIdx.x];
    __syncthreads();
    int n = blockIdx.x * 256 + threadIdx.x;
    if (n >= NN) return;
    float h[HID];
    #pragma unroll
    for (int q = 0; q < 8; ++q) {
        float2 f0 = __half22float2(L1[(size_t)n * 8 + q]);
        float2 f1 = __half22float2(L1[APS + (size_t)n * 8 + q]);
        float2 f2 = __half22float2(L1[2 * APS + (size_t)n * 8 + q]);
        h[2 * q + 0] = fmaxf((f0.x + f1.x + f2.x) * (1.f / 3.f), 0.f);
        h[2 * q + 1] = fmaxf((f0.y + f1.y + f2.y) * (1.f / 3.f), 0.f);
    }
    float dv = dinv[n];
    #pragma unroll
    for (int k = 0; k < KS; ++k) {
        #pragma unroll
        for (int o = 0; o < OUTC; ++o) {
            float a = 0.f, r = bb[k * 2 + o];
            #pragma unroll
            for (int hh = 0; hh < HID; ++hh) {
                a += h[hh] * wi[k * 32 + hh * 2 + o];
                r += h[hh] * wr_[k * 32 + hh * 2 + o];
            }
            A2[n * KO + k * 2 + o] = a * dv;
            R2[n * KO + k * 2 + o] = r;
        }
    }
}

// ---------------- SpMM 6-wide #1: fused 2x2 gemm (w2), output pre-scaled ----------------

__global__ void k_spmm6_g(const float* __restrict__ Asrc, const float* __restrict__ R2,
                          const int* __restrict__ row_start, const int* __restrict__ deg,
                          const float* __restrict__ dinv, const int* __restrict__ csr,
                          const float* __restrict__ w2, float* __restrict__ Bout) {
    __shared__ float ws[KS * OUTC * OUTC];
    if (threadIdx.x < KS * OUTC * OUTC) ws[threadIdx.x] = w2[threadIdx.x];
    __syncthreads();
    int t = blockIdx.x * 256 + threadIdx.x;
    int node = t / KO, j = t % KO;
    bool active = node < NN;
    float acc = 0.f, r = 0.f, dv = 0.f;
    int start = 0, d = 0;
    if (active) {
        start = row_start[node];
        d     = deg[node];
        r     = R2[node * KO + j];
        dv    = dinv[node];
    }
    int e = 0;
    for (; e + 4 <= d; e += 4) {
        int c0 = csr[start + e + 0];
        int c1 = csr[start + e + 1];
        int c2 = csr[start + e + 2];
        int c3 = csr[start + e + 3];
        acc += Asrc[c0 * KO + j];
        acc += Asrc[c1 * KO + j];
        acc += Asrc[c2 * KO + j];
        acc += Asrc[c3 * KO + j];
    }
    for (; e < d; ++e)
        acc += Asrc[csr[start + e] * KO + j];
    float v = acc * dv + r;
    float other = __shfl_xor(v, 1, 64);
    if (active) {
        int k = j >> 1, p = j & 1;
        float v0 = (p == 0) ? v : other;
        float v1 = (p == 0) ? other : v;
        Bout[node * KO + j] = (v0 * ws[k * 4 + p] + v1 * ws[k * 4 + 2 + p]) * dv;
    }
}

// ---------------- SpMM 6-wide #2: fused mean + log_softmax (10 nodes/wave) ----------------

__global__ void k_spmm6_f(const float* __restrict__ Asrc, const float* __restrict__ R2,
                          const int* __restrict__ row_start, const int* __restrict__ deg,
                          const float* __restrict__ dinv, const int* __restrict__ csr,
                          float* __restrict__ out) {
    int wave = threadIdx.x >> 6;
    int l    = threadIdx.x & 63;
    int nl   = l / 6;            // 0..10 (10 = inactive)
    int j    = l - nl * 6;
    bool active = nl < 10;
    int node = blockIdx.x * 40 + wave * 10 + nl;
    float acc = 0.f, r = 0.f, dv = 0.f;
    int start = 0, d = 0;
    if (active) {
        start = row_start[node];
        d     = deg[node];
        r     = R2[node * KO + j];
        dv    = dinv[node];
    }
    int e = 0;
    for (; e + 4 <= d; e += 4) {
        int c0 = csr[start + e + 0];
        int c1 = csr[start + e + 1];
        int c2 = csr[start + e + 2];
        int c3 = csr[start + e + 3];
        acc += Asrc[c0 * KO + j];
        acc += Asrc[c1 * KO + j];
        acc += Asrc[c2 * KO + j];
        acc += Asrc[c3 * KO + j];
    }
    for (; e < d; ++e)
        acc += Asrc[csr[start + e] * KO + j];
    float v = acc * dv + r;
    int base = nl * 6;
    float o0 = (__shfl(v, base + 0, 64) + __shfl(v, base + 2, 64) + __shfl(v, base + 4, 64)) * (1.f / 3.f);
    float o1 = (__shfl(v, base + 1, 64) + __shfl(v, base + 3, 64) + __shfl(v, base + 5, 64)) * (1.f / 3.f);
    if (active && j == 0) {
        float m = fmaxf(o0, o1);
        float ls = m + logf(expf(o0 - m) + expf(o1 - m));
        *(float2*)(out + (size_t)node * 2) = make_float2(o0 - ls, o1 - ls);
    }
}

// ---------------- host ----------------

extern "C" void kernel_launch(void* const* d_in, const int* in_sizes, int n_in,
                              void* d_out, int out_size, void* d_ws, size_t ws_size,
                              hipStream_t stream) {
    const float* x   = (const float*)d_in[0];
    const int*   ei  = (const int*)d_in[1];
    const float* iw1 = (const float*)d_in[2];
    const float* w1  = (const float*)d_in[3];
    const float* rw1 = (const float*)d_in[4];
    const float* b1  = (const float*)d_in[5];
    const float* iw2 = (const float*)d_in[6];
    const float* w2  = (const float*)d_in[7];
    const float* rw2 = (const float*)d_in[8];
    const float* b2  = (const float*)d_in[9];
    const int* src = ei;
    const int* dst = ei + NE;
    float* out = (float*)d_out;

    char* ws = (char*)d_ws;
    size_t o = 0;
    int*     deg       = (int*)(ws + o);     o += (size_t)NN * 4;
    int*     row_start = (int*)(ws + o);     o += (size_t)NN * 4;
    float*   dinv      = (float*)(ws + o);   o += (size_t)NN * 4;
    int*     hist      = (int*)(ws + o);     o += (size_t)M1 * 4;
    int*     hist_scan = (int*)(ws + o);     o += (size_t)M1 * 4;
    int*     partials  = (int*)(ws + o);     o += 128 * 4;
    int*     csr       = (int*)(ws + o);     o += (size_t)CSR_CAP * 4;   // 15.6MB pad-8 CSR
    __half2* Ap        = (__half2*)(ws + o); o += 3 * APS * 4;           // 9.6MB (3 planes)
    __half2* Rp        = (__half2*)(ws + o); o += 3 * RPS * 4;           // 9.6MB (3 planes)
    __half2* Bp        = (__half2*)(ws + o); o += 3 * APS * 4;           // 9.6MB (3 planes)
    // overlays
    int*    recs  = (int*)Ap;                // 12.8MB spans Ap + head of Rp; dead before transform1
    __half2* L1f  = Ap;                      // spmm16<false> output planes (reads Bp, not Ap)
    float*  A2    = (float*)Rp;              // layer-2 buffers live in Rp (dead after spmm16<false>)
    float*  R2    = (float*)Rp + (size_t)NN * KO;
    float*  C2    = (float*)Rp + (size_t)NN * KO * 2;   // 7.2MB <= 9.6MB

    // ---- CSR build (5 dispatches) ----
    k_hist       <<<PB, 256, 0, stream>>>(dst, hist);
    k_partial    <<<NSCB, 256, 0, stream>>>(hist, partials, M1);
    k_downsweepF <<<NSCB, 256, 0, stream>>>(hist, partials, hist_scan, M1);
    k_pass2      <<<PB, 256, 0, stream>>>(src, dst, hist_scan, recs);
    k_degsort    <<<NBINS, BINW, 0, stream>>>(recs, hist_scan, deg, dinv, row_start, csr);

    // ---- layer 1 ----
    k_transform1 <<<TNB + 1, 256, 0, stream>>>(x, iw1, rw1, b1, dinv, Ap, Bp, Rp);
    // propagate #1 + fused w1 gemm: one phase per stack (3.2MB plane -> L2-resident)
    for (int k = 0; k < KS; ++k)
        k_spmm16<true><<<NN / 4, 256, 0, stream>>>(Ap + k * APS, Rp + k * RPS,
                                                   row_start, deg, dinv, csr,
                                                   w1 + k * 256, Bp + k * APS);
    // propagate #2 (no gemm): output L1 planes into Ap region
    for (int k = 0; k < KS; ++k)
        k_spmm16<false><<<NN / 4, 256, 0, stream>>>(Bp + k * APS, Rp + k * RPS,
                                                    row_start, deg, dinv, csr,
                                                    w1, L1f + k * APS);

    // ---- layer 2 ----
    k_mt2     <<<(NN + 255) / 256, 256, 0, stream>>>(L1f, iw2, rw2, b2, dinv, A2, R2);
    k_spmm6_g <<<(NN * KO + 255) / 256, 256, 0, stream>>>(A2, R2, row_start, deg, dinv, csr, w2, C2);
    k_spmm6_f <<<NN / 40, 256, 0, stream>>>(C2, R2, row_start, deg, dinv, csr, out);
}

// Round 11
// 319.264 us; speedup vs baseline: 1.3569x; 1.3569x over previous
//
#include <hip/hip_runtime.h>
#include <hip/hip_fp16.h>
#include <math.h>

#define NN 100000
#define NE 3200000
#define FEA 67
#define HID 16
#define OUTC 2
#define KS 3
#define KH 48   /* KS*HID */
#define KO 6    /* KS*OUTC */
#define PAD 64  /* padded fp16 row stride: 128B = 1 cache line */

#define PB 512          /* partition blocks */
#define EPB 6250        /* edges per partition block (PB*EPB == NE) */
#define BINW 512        /* nodes per bin */
#define NBINS 196       /* ceil(NN/BINW) */
#define M1 (NBINS * PB) /* 100352 */
#define NSCB 98         /* scan blocks: 98*1024 == M1 exactly */
#define CSR_CAP (NE + NBINS * 3 * BINW + 64)   /* pad-4 CSR capacity */

#define T1B 1563        /* t1 blocks per half: 1563*64 >= NN */

// ---------------- partition: histogram ----------------

__global__ void k_hist(const int* __restrict__ dst, int* __restrict__ hist) {
    __shared__ int h[NBINS];
    if (threadIdx.x < NBINS) h[threadIdx.x] = 0;
    __syncthreads();
    int base = blockIdx.x * EPB;
    for (int i = threadIdx.x; i < EPB; i += 256)
        atomicAdd(&h[dst[base + i] >> 9], 1);
    __syncthreads();
    if (threadIdx.x < NBINS) hist[threadIdx.x * PB + blockIdx.x] = h[threadIdx.x];
}

// ---------------- 2-kernel exclusive scan ----------------

__global__ void k_partial(const int* __restrict__ in, int* __restrict__ partials, int n) {
    __shared__ int s[256];
    int base = blockIdx.x * 1024;
    int acc = 0;
    for (int i = threadIdx.x; i < 1024; i += 256) {
        int idx = base + i;
        if (idx < n) acc += in[idx];
    }
    s[threadIdx.x] = acc;
    __syncthreads();
    for (int off = 128; off > 0; off >>= 1) {
        if (threadIdx.x < off) s[threadIdx.x] += s[threadIdx.x + off];
        __syncthreads();
    }
    if (threadIdx.x == 0) partials[blockIdx.x] = s[0];
}

__global__ void k_downsweepF(const int* __restrict__ in, const int* __restrict__ partials,
                             int* __restrict__ out, int n) {
    __shared__ int ps[256];
    __shared__ int s[256];
    int t = threadIdx.x;
    ps[t] = (t < NSCB) ? partials[t] : 0;
    __syncthreads();
    for (int off = 1; off < 256; off <<= 1) {
        int v = (t >= off) ? ps[t - off] : 0;
        __syncthreads();
        ps[t] += v;
        __syncthreads();
    }
    int bbase = (blockIdx.x > 0) ? ps[blockIdx.x - 1] : 0;

    int base = blockIdx.x * 1024 + t * 4;
    int d0 = 0, d1 = 0, d2 = 0, d3 = 0;
    if (base + 0 < n) d0 = in[base + 0];
    if (base + 1 < n) d1 = in[base + 1];
    if (base + 2 < n) d2 = in[base + 2];
    if (base + 3 < n) d3 = in[base + 3];
    int ts = d0 + d1 + d2 + d3;
    s[t] = ts;
    __syncthreads();
    for (int off = 1; off < 256; off <<= 1) {
        int v = (t >= off) ? s[t - off] : 0;
        __syncthreads();
        s[t] += v;
        __syncthreads();
    }
    int excl = s[t] - ts + bbase;
    if (base + 0 < n) out[base + 0] = excl;
    if (base + 1 < n) out[base + 1] = excl + d0;
    if (base + 2 < n) out[base + 2] = excl + d0 + d1;
    if (base + 3 < n) out[base + 3] = excl + d0 + d1 + d2;
}

// ---------------- partition: scatter to bins ----------------

__global__ void k_pass2(const int* __restrict__ src, const int* __restrict__ dst,
                        const int* __restrict__ hist_scan, int* __restrict__ recs) {
    __shared__ int curs[NBINS];
    if (threadIdx.x < NBINS) curs[threadIdx.x] = hist_scan[threadIdx.x * PB + blockIdx.x];
    __syncthreads();
    int base = blockIdx.x * EPB;
    for (int i = threadIdx.x; i < EPB; i += 256) {
        int e = base + i;
        int s = src[e], d = dst[e];
        int pos = atomicAdd(&curs[d >> 9], 1);
        recs[pos] = s | ((d & 511) << 17);            // src:17b | dst_local:9b
    }
}

// ---------------- fused per-bin: degree + dinv + pad-4 row_start + CSR scatter ----------------

__global__ void k_degsort(const int* __restrict__ recs, const int* __restrict__ hist_scan,
                          int* __restrict__ deg, float* __restrict__ dinv,
                          int* __restrict__ row_start, int* __restrict__ csr) {
    __shared__ int cnt[BINW];
    __shared__ int scn[BINW];
    int bin = blockIdx.x, t = threadIdx.x;
    cnt[t] = 0;
    __syncthreads();
    int s0 = hist_scan[bin * PB];
    int s1 = (bin + 1 < NBINS) ? hist_scan[(bin + 1) * PB] : NE;
    for (int r = s0 + t; r < s1; r += BINW)
        atomicAdd(&cnt[((unsigned)recs[r]) >> 17], 1);
    __syncthreads();
    int c  = cnt[t];
    int c4 = (c + 3) & ~3;
    scn[t] = c4;
    __syncthreads();
    for (int off = 1; off < BINW; off <<= 1) {
        int v = (t >= off) ? scn[t - off] : 0;
        __syncthreads();
        scn[t] += v;
        __syncthreads();
    }
    int base = s0 + bin * (3 * BINW);      // pad-4 region base for this bin
    int rs   = base + scn[t] - c4;         // exclusive padded prefix
    int node = bin * BINW + t;
    if (node < NN) {
        deg[node]       = c;
        dinv[node]      = (c > 0) ? rsqrtf((float)c) : 0.f;
        row_start[node] = rs;
    }
    scn[t] = rs;                            // scatter cursor
    __syncthreads();
    for (int r = s0 + t; r < s1; r += BINW) {
        int rec = recs[r];
        int pos = atomicAdd(&scn[((unsigned)rec) >> 17], 1);
        csr[pos] = rec & 0x1FFFF;
    }
    __syncthreads();
    int e4 = rs + c4;
    for (int i = scn[t]; i < e4; ++i) csr[i] = NN;   // sentinel pads (zero row)
}

// ---------------- weight prep: transpose iw/rw -> wT[96][68]; zero A/B pad rows ----------------

__global__ void k_wprep(const float* __restrict__ iw, const float* __restrict__ rw,
                        float* __restrict__ wT, __half2* __restrict__ Ah, __half2* __restrict__ Bh) {
    int t = threadIdx.x;
    __half2 z = __halves2half2(__float2half(0.f), __float2half(0.f));
    if (t < 32)      Ah[(size_t)NN * 32 + t] = z;          // zero pad row NN of A
    else if (t < 64) Bh[(size_t)NN * 32 + (t - 32)] = z;   // zero pad row NN of B
    for (int idx = t; idx < KS * FEA * HID; idx += 256) {
        int k = idx / (FEA * HID);
        int r = idx - k * (FEA * HID);
        int f = r >> 4, h = r & 15;
        int j = k * 16 + h;
        float vi = iw[idx], vr = rw[idx];
        wT[j * 68 + f]        = vi;
        wT[(48 + j) * 68 + f] = vr;
    }
}

// ---------------- layer 1 dense transform: 64 nodes/block, half-split, full occupancy ----------------
// half 0: A[n][j] = (sum_f x*iw) * dinv[n]  -> fp16 pairs, row stride 32 half2
// half 1: R[n][j] =  sum_f x*rw + b1[j]     -> fp16 pairs, row stride 24 half2

__global__ void k_t1(const float* __restrict__ x, const float* __restrict__ wT,
                     const float* __restrict__ b1, const float* __restrict__ dinv,
                     __half2* __restrict__ Ah, __half2* __restrict__ Rh) {
    __shared__ float xs[64 * 68];    // 17408 B
    __shared__ float wls[48 * 68];   // 13056 B
    __shared__ float bbs[48];
    int half = blockIdx.y;
    int n0   = blockIdx.x * 64;
    const float* wsrc = wT + half * (48 * 68);
    for (int idx = threadIdx.x; idx < 48 * 68; idx += 256) wls[idx] = wsrc[idx];
    for (int idx = threadIdx.x; idx < 64 * FEA; idx += 256) {
        int nl = idx / FEA, f = idx - nl * FEA;
        int n = n0 + nl;
        xs[nl * 68 + f] = (n < NN) ? x[(size_t)n0 * FEA + idx] : 0.f;
    }
    if (half && threadIdx.x < 48) bbs[threadIdx.x] = b1[threadIdx.x];
    __syncthreads();

    int nl = threadIdx.x >> 2, cg = threadIdx.x & 3;
    int n  = n0 + nl;
    float acc[12];
    #pragma unroll
    for (int p = 0; p < 12; ++p) acc[p] = 0.f;
    if (half) {
        #pragma unroll
        for (int p = 0; p < 12; ++p) acc[p] = bbs[cg * 12 + p];
    }
    const float* xr = &xs[nl * 68];
    const float* wb = &wls[cg * 12 * 68];
    #pragma unroll 4
    for (int fb = 0; fb < 16; ++fb) {
        int f0 = fb * 4;
        float4 xv = *(const float4*)&xr[f0];
        #pragma unroll
        for (int p = 0; p < 12; ++p) {
            float4 wv = *(const float4*)&wb[p * 68 + f0];
            acc[p] += xv.x * wv.x + xv.y * wv.y + xv.z * wv.z + xv.w * wv.w;
        }
    }
    #pragma unroll
    for (int f = 64; f < FEA; ++f) {
        float xv = xr[f];
        #pragma unroll
        for (int p = 0; p < 12; ++p) acc[p] += xv * wb[p * 68 + f];
    }

    if (n < NN) {
        if (half == 0) {
            float dv = dinv[n];
            #pragma unroll
            for (int p2 = 0; p2 < 6; ++p2)
                Ah[(size_t)n * 32 + cg * 6 + p2] =
                    __halves2half2(__float2half_rn(acc[2 * p2] * dv),
                                   __float2half_rn(acc[2 * p2 + 1] * dv));
        } else {
            #pragma unroll
            for (int p2 = 0; p2 < 6; ++p2)
                Rh[(size_t)n * 24 + cg * 6 + p2] =
                    __halves2half2(__float2half_rn(acc[2 * p2]),
                                   __float2half_rn(acc[2 * p2 + 1]));
        }
    }
}

// ---------------- SpMM 48-wide: round-9 pair scheme + pad-4 CSR ----------------

template <bool FUSEW>
__global__ void k_spmm48(const __half2* __restrict__ Asrc,   // row stride PAD/2 half2
                         const __half2* __restrict__ Rh,     // row stride 24 half2
                         const int* __restrict__ row_start, const int* __restrict__ deg,
                         const float* __restrict__ dinv, const int* __restrict__ csr,
                         const float* __restrict__ w1, __half2* __restrict__ Bout) {
    __shared__ float w1s[FUSEW ? KS * HID * HID : 1];
    if (FUSEW) {
        for (int i = threadIdx.x; i < KS * HID * HID; i += 256) w1s[i] = w1[i];
        __syncthreads();
    }
    int node = (blockIdx.x * 256 + threadIdx.x) >> 6;   // one wave per node
    int lane = threadIdx.x & 63;
    int eo   = lane >> 5;           // edge parity within pair
    int cl   = lane & 31;           // col-pair index (cols 2cl, 2cl+1)
    int start = __builtin_amdgcn_readfirstlane(row_start[node]);
    int d     = __builtin_amdgcn_readfirstlane(deg[node]);
    int d4    = (d + 3) & ~3;       // csr padded with NN sentinels (zero row)
    float dv  = dinv[node];
    float2 r2 = make_float2(0.f, 0.f);
    if (cl < 24) r2 = __half22float2(Rh[(size_t)node * 24 + cl]);

    float ax = 0.f, ay = 0.f;
    for (int b = 0; b < d4; b += 64) {
        int nb  = min(64, d4 - b);              // multiple of 4
        int myc = csr[start + b + lane];        // unguarded: padded CSR + slack
        int npf = nb >> 1;                      // pairs, multiple of 2
        int p = 0;
        for (; p + 4 <= npf; p += 4) {
            int c0 = __shfl(myc, 2 * (p + 0) + eo, 64);
            int c1 = __shfl(myc, 2 * (p + 1) + eo, 64);
            int c2 = __shfl(myc, 2 * (p + 2) + eo, 64);
            int c3 = __shfl(myc, 2 * (p + 3) + eo, 64);
            float2 f0 = __half22float2(Asrc[(size_t)c0 * (PAD / 2) + cl]);
            float2 f1 = __half22float2(Asrc[(size_t)c1 * (PAD / 2) + cl]);
            float2 f2 = __half22float2(Asrc[(size_t)c2 * (PAD / 2) + cl]);
            float2 f3 = __half22float2(Asrc[(size_t)c3 * (PAD / 2) + cl]);
            ax += f0.x + f1.x; ay += f0.y + f1.y;
            ax += f2.x + f3.x; ay += f2.y + f3.y;
        }
        for (; p < npf; ++p) {
            int c = __shfl(myc, 2 * p + eo, 64);
            float2 f = __half22float2(Asrc[(size_t)c * (PAD / 2) + cl]);
            ax += f.x; ay += f.y;
        }
    }
    // combine edge parities
    ax += __shfl_xor(ax, 32, 64);
    ay += __shfl_xor(ay, 32, 64);
    // root + relu (both layer-1 propagates end in relu)
    float vx = fmaxf(ax * dv + r2.x, 0.f);
    float vy = fmaxf(ay * dv + r2.y, 0.f);

    if (FUSEW) {
        // out[k*16+p0], out[k*16+p0+1] = sum_h in[k*16+h] * w1[k][h][p]
        int k  = cl >> 3;              // (2cl)>>4
        int p0 = (2 * cl) & 15;
        float o0 = 0.f, o1 = 0.f;
        #pragma unroll
        for (int h2 = 0; h2 < 8; ++h2) {
            float ix = __shfl(vx, k * 8 + h2, 64);   // in[k*16 + 2h2]
            float iy = __shfl(vy, k * 8 + h2, 64);   // in[k*16 + 2h2+1]
            o0 += ix * w1s[k * 256 + (2 * h2) * 16 + p0]     + iy * w1s[k * 256 + (2 * h2 + 1) * 16 + p0];
            o1 += ix * w1s[k * 256 + (2 * h2) * 16 + p0 + 1] + iy * w1s[k * 256 + (2 * h2 + 1) * 16 + p0 + 1];
        }
        if (eo == 0 && cl < 24)
            Bout[(size_t)node * (PAD / 2) + cl] =
                __halves2half2(__float2half_rn(o0 * dv), __float2half_rn(o1 * dv));
    } else {
        if (eo == 0 && cl < 24)
            Bout[(size_t)node * (PAD / 2) + cl] =
                __halves2half2(__float2half_rn(vx), __float2half_rn(vy));
    }
}

// ---------------- fused mean+relu+transform2 ----------------

__global__ void k_mt2(const __half* __restrict__ L1, const float* __restrict__ iw,
                      const float* __restrict__ rw, const float* __restrict__ b2,
                      const float* __restrict__ dinv,
                      float* __restrict__ A2, float* __restrict__ R2) {
    __shared__ float wi[KS * HID * OUTC];
    __shared__ float wr_[KS * HID * OUTC];
    __shared__ float bb[KO];
    if (threadIdx.x < KS * HID * OUTC) { wi[threadIdx.x] = iw[threadIdx.x]; wr_[threadIdx.x] = rw[threadIdx.x]; }
    if (threadIdx.x < KO) bb[threadIdx.x] = b2[threadIdx.x];
    __syncthreads();
    int n = blockIdx.x * 256 + threadIdx.x;
    if (n >= NN) return;
    const __half2* hp = (const __half2*)(L1 + (size_t)n * PAD);
    float v[KH];
    #pragma unroll
    for (int q = 0; q < 24; ++q) {
        float2 f = __half22float2(hp[q]);
        v[q * 2 + 0] = f.x; v[q * 2 + 1] = f.y;
    }
    float h[HID];
    #pragma unroll
    for (int hh = 0; hh < HID; ++hh)
        h[hh] = fmaxf((v[hh] + v[16 + hh] + v[32 + hh]) * (1.f / 3.f), 0.f);
    float dv = dinv[n];
    #pragma unroll
    for (int k = 0; k < KS; ++k) {
        #pragma unroll
        for (int o = 0; o < OUTC; ++o) {
            float a = 0.f, r = bb[k * 2 + o];
            #pragma unroll
            for (int hh = 0; hh < HID; ++hh) {
                a += h[hh] * wi[k * 32 + hh * 2 + o];
                r += h[hh] * wr_[k * 32 + hh * 2 + o];
            }
            A2[n * KO + k * 2 + o] = a * dv;
            R2[n * KO + k * 2 + o] = r;
        }
    }
}

// ---------------- SpMM 6-wide #1: fused 2x2 gemm (w2), output pre-scaled ----------------

__global__ void k_spmm6_g(const float* __restrict__ Asrc, const float* __restrict__ R2,
                          const int* __restrict__ row_start, const int* __restrict__ deg,
                          const float* __restrict__ dinv, const int* __restrict__ csr,
                          const float* __restrict__ w2, float* __restrict__ Bout) {
    __shared__ float ws[KS * OUTC * OUTC];
    if (threadIdx.x < KS * OUTC * OUTC) ws[threadIdx.x] = w2[threadIdx.x];
    __syncthreads();
    int t = blockIdx.x * 256 + threadIdx.x;
    int node = t / KO, j = t % KO;
    bool active = node < NN;
    float acc = 0.f, r = 0.f, dv = 0.f;
    int start = 0, d = 0;
    if (active) {
        start = row_start[node];
        d     = deg[node];
        r     = R2[node * KO + j];
        dv    = dinv[node];
    }
    int e = 0;
    for (; e + 4 <= d; e += 4) {
        int c0 = csr[start + e + 0];
        int c1 = csr[start + e + 1];
        int c2 = csr[start + e + 2];
        int c3 = csr[start + e + 3];
        acc += Asrc[c0 * KO + j];
        acc += Asrc[c1 * KO + j];
        acc += Asrc[c2 * KO + j];
        acc += Asrc[c3 * KO + j];
    }
    for (; e < d; ++e)
        acc += Asrc[csr[start + e] * KO + j];
    float v = acc * dv + r;
    float other = __shfl_xor(v, 1, 64);
    if (active) {
        int k = j >> 1, p = j & 1;
        float v0 = (p == 0) ? v : other;
        float v1 = (p == 0) ? other : v;
        Bout[node * KO + j] = (v0 * ws[k * 4 + p] + v1 * ws[k * 4 + 2 + p]) * dv;
    }
}

// ---------------- SpMM 6-wide #2: fused mean + log_softmax (10 nodes/wave) ----------------

__global__ void k_spmm6_f(const float* __restrict__ Asrc, const float* __restrict__ R2,
                          const int* __restrict__ row_start, const int* __restrict__ deg,
                          const float* __restrict__ dinv, const int* __restrict__ csr,
                          float* __restrict__ out) {
    int wave = threadIdx.x >> 6;
    int l    = threadIdx.x & 63;
    int nl   = l / 6;            // 0..10 (10 = inactive)
    int j    = l - nl * 6;
    bool active = nl < 10;
    int node = blockIdx.x * 40 + wave * 10 + nl;
    float acc = 0.f, r = 0.f, dv = 0.f;
    int start = 0, d = 0;
    if (active) {
        start = row_start[node];
        d     = deg[node];
        r     = R2[node * KO + j];
        dv    = dinv[node];
    }
    int e = 0;
    for (; e + 4 <= d; e += 4) {
        int c0 = csr[start + e + 0];
        int c1 = csr[start + e + 1];
        int c2 = csr[start + e + 2];
        int c3 = csr[start + e + 3];
        acc += Asrc[c0 * KO + j];
        acc += Asrc[c1 * KO + j];
        acc += Asrc[c2 * KO + j];
        acc += Asrc[c3 * KO + j];
    }
    for (; e < d; ++e)
        acc += Asrc[csr[start + e] * KO + j];
    float v = acc * dv + r;
    int base = nl * 6;
    float o0 = (__shfl(v, base + 0, 64) + __shfl(v, base + 2, 64) + __shfl(v, base + 4, 64)) * (1.f / 3.f);
    float o1 = (__shfl(v, base + 1, 64) + __shfl(v, base + 3, 64) + __shfl(v, base + 5, 64)) * (1.f / 3.f);
    if (active && j == 0) {
        float m = fmaxf(o0, o1);
        float ls = m + logf(expf(o0 - m) + expf(o1 - m));
        *(float2*)(out + (size_t)node * 2) = make_float2(o0 - ls, o1 - ls);
    }
}

// ---------------- host ----------------

extern "C" void kernel_launch(void* const* d_in, const int* in_sizes, int n_in,
                              void* d_out, int out_size, void* d_ws, size_t ws_size,
                              hipStream_t stream) {
    const float* x   = (const float*)d_in[0];
    const int*   ei  = (const int*)d_in[1];
    const float* iw1 = (const float*)d_in[2];
    const float* w1  = (const float*)d_in[3];
    const float* rw1 = (const float*)d_in[4];
    const float* b1  = (const float*)d_in[5];
    const float* iw2 = (const float*)d_in[6];
    const float* w2  = (const float*)d_in[7];
    const float* rw2 = (const float*)d_in[8];
    const float* b2  = (const float*)d_in[9];
    const int* src = ei;
    const int* dst = ei + NE;
    float* out = (float*)d_out;

    char* ws = (char*)d_ws;
    size_t o = 0;
    int*     deg       = (int*)(ws + o);     o += (size_t)NN * 4;
    int*     row_start = (int*)(ws + o);     o += (size_t)NN * 4;
    float*   dinv      = (float*)(ws + o);   o += (size_t)NN * 4;
    int*     hist      = (int*)(ws + o);     o += (size_t)M1 * 4;
    int*     hist_scan = (int*)(ws + o);     o += (size_t)M1 * 4;
    int*     partials  = (int*)(ws + o);     o += 128 * 4;
    int*     csr       = (int*)(ws + o);     o += (size_t)CSR_CAP * 4;         // 14MB pad-4 CSR
    __half*  A         = (__half*)(ws + o);  o += (size_t)(NN + 1) * PAD * 2;  // 12.8MB
    __half2* Rh        = (__half2*)(ws + o); o += (size_t)NN * 24 * 4;         // 9.6MB fp16 R
    __half*  B         = (__half*)(ws + o);  o += (size_t)(NN + 1) * PAD * 2;  // 12.8MB
    float*   wT        = (float*)(ws + o);   o += 96 * 68 * 4;                 // 26KB transposed weights
    // overlays
    int*    recs  = (int*)A;                 // NE*4 = 12.8MB fits in A region; dead before t1
    __half* L1f   = A;                       // spmm48#2 output (reads B, not A)
    float*  A2    = (float*)Rh;              // layer-2 buffers live in Rh (dead after spmm48#2)
    float*  R2    = (float*)Rh + (size_t)NN * KO;
    float*  C2    = (float*)Rh + (size_t)NN * KO * 2;   // 7.2MB <= 9.6MB

    // ---- CSR build (5 dispatches) ----
    k_hist       <<<PB, 256, 0, stream>>>(dst, hist);
    k_partial    <<<NSCB, 256, 0, stream>>>(hist, partials, M1);
    k_downsweepF <<<NSCB, 256, 0, stream>>>(hist, partials, hist_scan, M1);
    k_pass2      <<<PB, 256, 0, stream>>>(src, dst, hist_scan, recs);
    k_degsort    <<<NBINS, BINW, 0, stream>>>(recs, hist_scan, deg, dinv, row_start, csr);

    // ---- layer 1 ----
    k_wprep <<<1, 256, 0, stream>>>(iw1, rw1, wT, (__half2*)A, (__half2*)B);
    k_t1    <<<dim3(T1B, 2), 256, 0, stream>>>(x, wT, b1, dinv, (__half2*)A, Rh);
    k_spmm48<true>  <<<NN / 4, 256, 0, stream>>>((const __half2*)A, Rh, row_start, deg, dinv, csr, w1, (__half2*)B);
    k_spmm48<false> <<<NN / 4, 256, 0, stream>>>((const __half2*)B, Rh, row_start, deg, dinv, csr, w1, (__half2*)L1f);

    // ---- layer 2 ----
    k_mt2     <<<(NN + 255) / 256, 256, 0, stream>>>(L1f, iw2, rw2, b2, dinv, A2, R2);
    k_spmm6_g <<<(NN * KO + 255) / 256, 256, 0, stream>>>(A2, R2, row_start, deg, dinv, csr, w2, C2);
    k_spmm6_f <<<NN / 40, 256, 0, stream>>>(C2, R2, row_start, deg, dinv, csr, out);
}

// Round 12
// 311.948 us; speedup vs baseline: 1.3888x; 1.0235x over previous
//
#include <hip/hip_runtime.h>
#include <hip/hip_fp16.h>
#include <math.h>

#define NN 100000
#define NE 3200000
#define FEA 67
#define HID 16
#define OUTC 2
#define KS 3
#define KH 48   /* KS*HID */
#define KO 6    /* KS*OUTC */
#define PAD 64  /* padded fp16 row stride: 128B = 1 cache line */

#define PB 512          /* partition blocks */
#define EPB 6250        /* edges per partition block (PB*EPB == NE) */
#define BINW 512        /* nodes per bin */
#define NBINS 196       /* ceil(NN/BINW) */
#define M1 (NBINS * PB) /* 100352 */
#define NSCB 98         /* scan blocks: 98*1024 == M1 exactly */
#define CSR_CAP (NE + NBINS * 3 * BINW + 64)   /* pad-4 CSR capacity */

#define T1B 1563        /* t1 blocks per half: 1563*64 >= NN */

typedef _Float16 f16x2 __attribute__((ext_vector_type(2)));

// ---------------- partition: histogram ----------------

__global__ void k_hist(const int* __restrict__ dst, int* __restrict__ hist) {
    __shared__ int h[NBINS];
    if (threadIdx.x < NBINS) h[threadIdx.x] = 0;
    __syncthreads();
    int base = blockIdx.x * EPB;
    for (int i = threadIdx.x; i < EPB; i += 256)
        atomicAdd(&h[dst[base + i] >> 9], 1);
    __syncthreads();
    if (threadIdx.x < NBINS) hist[threadIdx.x * PB + blockIdx.x] = h[threadIdx.x];
}

// ---------------- 2-kernel exclusive scan ----------------

__global__ void k_partial(const int* __restrict__ in, int* __restrict__ partials, int n) {
    __shared__ int s[256];
    int base = blockIdx.x * 1024;
    int acc = 0;
    for (int i = threadIdx.x; i < 1024; i += 256) {
        int idx = base + i;
        if (idx < n) acc += in[idx];
    }
    s[threadIdx.x] = acc;
    __syncthreads();
    for (int off = 128; off > 0; off >>= 1) {
        if (threadIdx.x < off) s[threadIdx.x] += s[threadIdx.x + off];
        __syncthreads();
    }
    if (threadIdx.x == 0) partials[blockIdx.x] = s[0];
}

__global__ void k_downsweepF(const int* __restrict__ in, const int* __restrict__ partials,
                             int* __restrict__ out, int n) {
    __shared__ int ps[256];
    __shared__ int s[256];
    int t = threadIdx.x;
    ps[t] = (t < NSCB) ? partials[t] : 0;
    __syncthreads();
    for (int off = 1; off < 256; off <<= 1) {
        int v = (t >= off) ? ps[t - off] : 0;
        __syncthreads();
        ps[t] += v;
        __syncthreads();
    }
    int bbase = (blockIdx.x > 0) ? ps[blockIdx.x - 1] : 0;

    int base = blockIdx.x * 1024 + t * 4;
    int d0 = 0, d1 = 0, d2 = 0, d3 = 0;
    if (base + 0 < n) d0 = in[base + 0];
    if (base + 1 < n) d1 = in[base + 1];
    if (base + 2 < n) d2 = in[base + 2];
    if (base + 3 < n) d3 = in[base + 3];
    int ts = d0 + d1 + d2 + d3;
    s[t] = ts;
    __syncthreads();
    for (int off = 1; off < 256; off <<= 1) {
        int v = (t >= off) ? s[t - off] : 0;
        __syncthreads();
        s[t] += v;
        __syncthreads();
    }
    int excl = s[t] - ts + bbase;
    if (base + 0 < n) out[base + 0] = excl;
    if (base + 1 < n) out[base + 1] = excl + d0;
    if (base + 2 < n) out[base + 2] = excl + d0 + d1;
    if (base + 3 < n) out[base + 3] = excl + d0 + d1 + d2;
}

// ---------------- partition: scatter to bins ----------------

__global__ void k_pass2(const int* __restrict__ src, const int* __restrict__ dst,
                        const int* __restrict__ hist_scan, int* __restrict__ recs) {
    __shared__ int curs[NBINS];
    if (threadIdx.x < NBINS) curs[threadIdx.x] = hist_scan[threadIdx.x * PB + blockIdx.x];
    __syncthreads();
    int base = blockIdx.x * EPB;
    for (int i = threadIdx.x; i < EPB; i += 256) {
        int e = base + i;
        int s = src[e], d = dst[e];
        int pos = atomicAdd(&curs[d >> 9], 1);
        recs[pos] = s | ((d & 511) << 17);            // src:17b | dst_local:9b
    }
}

// ---------------- fused per-bin: degree + dinv + pad-4 row_start + CSR scatter ----------------

__global__ void k_degsort(const int* __restrict__ recs, const int* __restrict__ hist_scan,
                          int* __restrict__ deg, float* __restrict__ dinv,
                          int* __restrict__ row_start, int* __restrict__ csr) {
    __shared__ int cnt[BINW];
    __shared__ int scn[BINW];
    int bin = blockIdx.x, t = threadIdx.x;
    cnt[t] = 0;
    __syncthreads();
    int s0 = hist_scan[bin * PB];
    int s1 = (bin + 1 < NBINS) ? hist_scan[(bin + 1) * PB] : NE;
    for (int r = s0 + t; r < s1; r += BINW)
        atomicAdd(&cnt[((unsigned)recs[r]) >> 17], 1);
    __syncthreads();
    int c  = cnt[t];
    int c4 = (c + 3) & ~3;
    scn[t] = c4;
    __syncthreads();
    for (int off = 1; off < BINW; off <<= 1) {
        int v = (t >= off) ? scn[t - off] : 0;
        __syncthreads();
        scn[t] += v;
        __syncthreads();
    }
    int base = s0 + bin * (3 * BINW);      // pad-4 region base for this bin
    int rs   = base + scn[t] - c4;         // exclusive padded prefix
    int node = bin * BINW + t;
    if (node < NN) {
        deg[node]       = c;
        dinv[node]      = (c > 0) ? rsqrtf((float)c) : 0.f;
        row_start[node] = rs;
    }
    scn[t] = rs;                            // scatter cursor
    __syncthreads();
    for (int r = s0 + t; r < s1; r += BINW) {
        int rec = recs[r];
        int pos = atomicAdd(&scn[((unsigned)rec) >> 17], 1);
        csr[pos] = rec & 0x1FFFF;
    }
    __syncthreads();
    int e4 = rs + c4;
    for (int i = scn[t]; i < e4; ++i) csr[i] = NN;   // sentinel pads (zero row)
}

// ---------------- weight prep: transpose iw/rw -> wT[96][68]; zero A/B pad rows ----------------

__global__ void k_wprep(const float* __restrict__ iw, const float* __restrict__ rw,
                        float* __restrict__ wT, __half2* __restrict__ Ah, __half2* __restrict__ Bh) {
    int t = threadIdx.x;
    __half2 z = __halves2half2(__float2half(0.f), __float2half(0.f));
    if (t < 32)      Ah[(size_t)NN * 32 + t] = z;          // zero pad row NN of A
    else if (t < 64) Bh[(size_t)NN * 32 + (t - 32)] = z;   // zero pad row NN of B
    for (int idx = t; idx < KS * FEA * HID; idx += 256) {
        int k = idx / (FEA * HID);
        int r = idx - k * (FEA * HID);
        int f = r >> 4, h = r & 15;
        int j = k * 16 + h;
        float vi = iw[idx], vr = rw[idx];
        wT[j * 68 + f]        = vi;
        wT[(48 + j) * 68 + f] = vr;
    }
}

// ---------------- layer 1 dense transform: 64 nodes/block, half-split ----------------

__global__ void k_t1(const float* __restrict__ x, const float* __restrict__ wT,
                     const float* __restrict__ b1, const float* __restrict__ dinv,
                     __half2* __restrict__ Ah, __half2* __restrict__ Rh) {
    __shared__ float xs[64 * 68];    // 17408 B
    __shared__ float wls[48 * 68];   // 13056 B
    __shared__ float bbs[48];
    int half = blockIdx.y;
    int n0   = blockIdx.x * 64;
    const float* wsrc = wT + half * (48 * 68);
    for (int idx = threadIdx.x; idx < 48 * 68; idx += 256) wls[idx] = wsrc[idx];
    int lim = (NN - n0) * FEA;       // exact readable extent of this tile
    for (int idx = threadIdx.x; idx < 64 * FEA; idx += 256) {
        int nl = idx / FEA, f = idx - nl * FEA;
        xs[nl * 68 + f] = (idx < lim) ? x[(size_t)n0 * FEA + idx] : 0.f;
    }
    if (half && threadIdx.x < 48) bbs[threadIdx.x] = b1[threadIdx.x];
    __syncthreads();

    int nl = threadIdx.x >> 2, cg = threadIdx.x & 3;
    int n  = n0 + nl;
    float acc[12];
    #pragma unroll
    for (int p = 0; p < 12; ++p) acc[p] = 0.f;
    if (half) {
        #pragma unroll
        for (int p = 0; p < 12; ++p) acc[p] = bbs[cg * 12 + p];
    }
    const float* xr = &xs[nl * 68];
    const float* wb = &wls[cg * 12 * 68];
    #pragma unroll 4
    for (int fb = 0; fb < 16; ++fb) {
        int f0 = fb * 4;
        float4 xv = *(const float4*)&xr[f0];
        #pragma unroll
        for (int p = 0; p < 12; ++p) {
            float4 wv = *(const float4*)&wb[p * 68 + f0];
            acc[p] += xv.x * wv.x + xv.y * wv.y + xv.z * wv.z + xv.w * wv.w;
        }
    }
    #pragma unroll
    for (int f = 64; f < FEA; ++f) {
        float xv = xr[f];
        #pragma unroll
        for (int p = 0; p < 12; ++p) acc[p] += xv * wb[p * 68 + f];
    }

    if (n < NN) {
        if (half == 0) {
            float dv = dinv[n];
            #pragma unroll
            for (int p2 = 0; p2 < 6; ++p2)
                Ah[(size_t)n * 32 + cg * 6 + p2] =
                    __halves2half2(__float2half_rn(acc[2 * p2] * dv),
                                   __float2half_rn(acc[2 * p2 + 1] * dv));
        } else {
            #pragma unroll
            for (int p2 = 0; p2 < 6; ++p2)
                Rh[(size_t)n * 24 + cg * 6 + p2] =
                    __halves2half2(__float2half_rn(acc[2 * p2]),
                                   __float2half_rn(acc[2 * p2 + 1]));
        }
    }
}

// ---------------- SpMM 48-wide: pair scheme, LDS-chunk broadcast + fdot2 + 32-bit addr ----------------

template <bool FUSEW>
__global__ void k_spmm48(const f16x2* __restrict__ Asrc,    // row stride 32 f16x2
                         const __half2* __restrict__ Rh,    // row stride 24 half2
                         const int* __restrict__ row_start, const int* __restrict__ deg,
                         const float* __restrict__ dinv, const int* __restrict__ csr,
                         const float* __restrict__ w1, __half2* __restrict__ Bout) {
    __shared__ float w1s[FUSEW ? KS * HID * HID : 1];
    __shared__ int chunk[4][64];
    if (FUSEW) {
        for (int i = threadIdx.x; i < KS * HID * HID; i += 256) w1s[i] = w1[i];
        __syncthreads();
    }
    int wv   = threadIdx.x >> 6;
    int node = (blockIdx.x * 256 + threadIdx.x) >> 6;   // one wave per node
    int lane = threadIdx.x & 63;
    int eo   = lane >> 5;           // edge parity within pair
    int cl   = lane & 31;           // col-pair index (cols 2cl, 2cl+1)
    int start = __builtin_amdgcn_readfirstlane(row_start[node]);
    int d     = __builtin_amdgcn_readfirstlane(deg[node]);
    int d4    = (d + 3) & ~3;       // csr padded with NN sentinels (zero row)
    float dv  = dinv[node];
    float2 r2 = make_float2(0.f, 0.f);
    if (cl < 24) r2 = __half22float2(Rh[(size_t)node * 24 + cl]);

    f16x2 h10 = {(_Float16)1.f, (_Float16)0.f};
    f16x2 h01 = {(_Float16)0.f, (_Float16)1.f};
    int* ch = &chunk[wv][0];
    const int* cp = ch + eo;        // read base: +eo*4 bytes; pair p at offset 8p
    float ax = 0.f, ay = 0.f;
    for (int b = 0; b < d4; b += 64) {
        int nb  = min(64, d4 - b);              // multiple of 4
        ch[lane] = csr[start + b + lane];       // wave-private stage (no barrier)
        int npf = nb >> 1;                      // pairs, multiple of 2
        int p = 0;
        for (; p + 4 <= npf; p += 4) {
            unsigned c0 = (unsigned)cp[2 * (p + 0)];
            unsigned c1 = (unsigned)cp[2 * (p + 1)];
            unsigned c2 = (unsigned)cp[2 * (p + 2)];
            unsigned c3 = (unsigned)cp[2 * (p + 3)];
            f16x2 f0 = Asrc[c0 * 32u + (unsigned)cl];
            f16x2 f1 = Asrc[c1 * 32u + (unsigned)cl];
            f16x2 f2 = Asrc[c2 * 32u + (unsigned)cl];
            f16x2 f3 = Asrc[c3 * 32u + (unsigned)cl];
            ax = __builtin_amdgcn_fdot2(f0, h10, ax, false);
            ay = __builtin_amdgcn_fdot2(f0, h01, ay, false);
            ax = __builtin_amdgcn_fdot2(f1, h10, ax, false);
            ay = __builtin_amdgcn_fdot2(f1, h01, ay, false);
            ax = __builtin_amdgcn_fdot2(f2, h10, ax, false);
            ay = __builtin_amdgcn_fdot2(f2, h01, ay, false);
            ax = __builtin_amdgcn_fdot2(f3, h10, ax, false);
            ay = __builtin_amdgcn_fdot2(f3, h01, ay, false);
        }
        for (; p < npf; ++p) {
            unsigned c = (unsigned)cp[2 * p];
            f16x2 f = Asrc[c * 32u + (unsigned)cl];
            ax = __builtin_amdgcn_fdot2(f, h10, ax, false);
            ay = __builtin_amdgcn_fdot2(f, h01, ay, false);
        }
    }
    // combine edge parities
    ax += __shfl_xor(ax, 32, 64);
    ay += __shfl_xor(ay, 32, 64);
    // root + relu (both layer-1 propagates end in relu)
    float vx = fmaxf(ax * dv + r2.x, 0.f);
    float vy = fmaxf(ay * dv + r2.y, 0.f);

    if (FUSEW) {
        // out[k*16+p0], out[k*16+p0+1] = sum_h in[k*16+h] * w1[k][h][p]
        int k  = cl >> 3;              // (2cl)>>4
        int p0 = (2 * cl) & 15;
        float o0 = 0.f, o1 = 0.f;
        #pragma unroll
        for (int h2 = 0; h2 < 8; ++h2) {
            float ix = __shfl(vx, k * 8 + h2, 64);   // in[k*16 + 2h2]
            float iy = __shfl(vy, k * 8 + h2, 64);   // in[k*16 + 2h2+1]
            o0 += ix * w1s[k * 256 + (2 * h2) * 16 + p0]     + iy * w1s[k * 256 + (2 * h2 + 1) * 16 + p0];
            o1 += ix * w1s[k * 256 + (2 * h2) * 16 + p0 + 1] + iy * w1s[k * 256 + (2 * h2 + 1) * 16 + p0 + 1];
        }
        if (eo == 0 && cl < 24)
            Bout[(size_t)node * (PAD / 2) + cl] =
                __halves2half2(__float2half_rn(o0 * dv), __float2half_rn(o1 * dv));
    } else {
        if (eo == 0 && cl < 24)
            Bout[(size_t)node * (PAD / 2) + cl] =
                __halves2half2(__float2half_rn(vx), __float2half_rn(vy));
    }
}

// ---------------- fused mean+relu+transform2 ----------------

__global__ void k_mt2(const __half* __restrict__ L1, const float* __restrict__ iw,
                      const float* __restrict__ rw, const float* __restrict__ b2,
                      const float* __restrict__ dinv,
                      float* __restrict__ A2, float* __restrict__ R2) {
    __shared__ float wi[KS * HID * OUTC];
    __shared__ float wr_[KS * HID * OUTC];
    __shared__ float bb[KO];
    if (threadIdx.x < KS * HID * OUTC) { wi[threadIdx.x] = iw[threadIdx.x]; wr_[threadIdx.x] = rw[threadIdx.x]; }
    if (threadIdx.x < KO) bb[threadIdx.x] = b2[threadIdx.x];
    __syncthreads();
    int n = blockIdx.x * 256 + threadIdx.x;
    if (n >= NN) return;
    const __half2* hp = (const __half2*)(L1 + (size_t)n * PAD);
    float v[KH];
    #pragma unroll
    for (int q = 0; q < 24; ++q) {
        float2 f = __half22float2(hp[q]);
        v[q * 2 + 0] = f.x; v[q * 2 + 1] = f.y;
    }
    float h[HID];
    #pragma unroll
    for (int hh = 0; hh < HID; ++hh)
        h[hh] = fmaxf((v[hh] + v[16 + hh] + v[32 + hh]) * (1.f / 3.f), 0.f);
    float dv = dinv[n];
    #pragma unroll
    for (int k = 0; k < KS; ++k) {
        #pragma unroll
        for (int o = 0; o < OUTC; ++o) {
            float a = 0.f, r = bb[k * 2 + o];
            #pragma unroll
            for (int hh = 0; hh < HID; ++hh) {
                a += h[hh] * wi[k * 32 + hh * 2 + o];
                r += h[hh] * wr_[k * 32 + hh * 2 + o];
            }
            A2[n * KO + k * 2 + o] = a * dv;
            R2[n * KO + k * 2 + o] = r;
        }
    }
}

// ---------------- SpMM 6-wide #1: fused 2x2 gemm (w2), output pre-scaled ----------------

__global__ void k_spmm6_g(const float* __restrict__ Asrc, const float* __restrict__ R2,
                          const int* __restrict__ row_start, const int* __restrict__ deg,
                          const float* __restrict__ dinv, const int* __restrict__ csr,
                          const float* __restrict__ w2, float* __restrict__ Bout) {
    __shared__ float ws[KS * OUTC * OUTC];
    if (threadIdx.x < KS * OUTC * OUTC) ws[threadIdx.x] = w2[threadIdx.x];
    __syncthreads();
    int t = blockIdx.x * 256 + threadIdx.x;
    int node = t / KO, j = t % KO;
    bool active = node < NN;
    float acc = 0.f, r = 0.f, dv = 0.f;
    int start = 0, d = 0;
    if (active) {
        start = row_start[node];
        d     = deg[node];
        r     = R2[node * KO + j];
        dv    = dinv[node];
    }
    int e = 0;
    for (; e + 4 <= d; e += 4) {
        int c0 = csr[start + e + 0];
        int c1 = csr[start + e + 1];
        int c2 = csr[start + e + 2];
        int c3 = csr[start + e + 3];
        acc += Asrc[c0 * KO + j];
        acc += Asrc[c1 * KO + j];
        acc += Asrc[c2 * KO + j];
        acc += Asrc[c3 * KO + j];
    }
    for (; e < d; ++e)
        acc += Asrc[csr[start + e] * KO + j];
    float v = acc * dv + r;
    float other = __shfl_xor(v, 1, 64);
    if (active) {
        int k = j >> 1, p = j & 1;
        float v0 = (p == 0) ? v : other;
        float v1 = (p == 0) ? other : v;
        Bout[node * KO + j] = (v0 * ws[k * 4 + p] + v1 * ws[k * 4 + 2 + p]) * dv;
    }
}

// ---------------- SpMM 6-wide #2: fused mean + log_softmax (10 nodes/wave) ----------------

__global__ void k_spmm6_f(const float* __restrict__ Asrc, const float* __restrict__ R2,
                          const int* __restrict__ row_start, const int* __restrict__ deg,
                          const float* __restrict__ dinv, const int* __restrict__ csr,
                          float* __restrict__ out) {
    int wave = threadIdx.x >> 6;
    int l    = threadIdx.x & 63;
    int nl   = l / 6;            // 0..10 (10 = inactive)
    int j    = l - nl * 6;
    bool active = nl < 10;
    int node = blockIdx.x * 40 + wave * 10 + nl;
    float acc = 0.f, r = 0.f, dv = 0.f;
    int start = 0, d = 0;
    if (active) {
        start = row_start[node];
        d     = deg[node];
        r     = R2[node * KO + j];
        dv    = dinv[node];
    }
    int e = 0;
    for (; e + 4 <= d; e += 4) {
        int c0 = csr[start + e + 0];
        int c1 = csr[start + e + 1];
        int c2 = csr[start + e + 2];
        int c3 = csr[start + e + 3];
        acc += Asrc[c0 * KO + j];
        acc += Asrc[c1 * KO + j];
        acc += Asrc[c2 * KO + j];
        acc += Asrc[c3 * KO + j];
    }
    for (; e < d; ++e)
        acc += Asrc[csr[start + e] * KO + j];
    float v = acc * dv + r;
    int base = nl * 6;
    float o0 = (__shfl(v, base + 0, 64) + __shfl(v, base + 2, 64) + __shfl(v, base + 4, 64)) * (1.f / 3.f);
    float o1 = (__shfl(v, base + 1, 64) + __shfl(v, base + 3, 64) + __shfl(v, base + 5, 64)) * (1.f / 3.f);
    if (active && j == 0) {
        float m = fmaxf(o0, o1);
        float ls = m + logf(expf(o0 - m) + expf(o1 - m));
        *(float2*)(out + (size_t)node * 2) = make_float2(o0 - ls, o1 - ls);
    }
}

// ---------------- host ----------------

extern "C" void kernel_launch(void* const* d_in, const int* in_sizes, int n_in,
                              void* d_out, int out_size, void* d_ws, size_t ws_size,
                              hipStream_t stream) {
    const float* x   = (const float*)d_in[0];
    const int*   ei  = (const int*)d_in[1];
    const float* iw1 = (const float*)d_in[2];
    const float* w1  = (const float*)d_in[3];
    const float* rw1 = (const float*)d_in[4];
    const float* b1  = (const float*)d_in[5];
    const float* iw2 = (const float*)d_in[6];
    const float* w2  = (const float*)d_in[7];
    const float* rw2 = (const float*)d_in[8];
    const float* b2  = (const float*)d_in[9];
    const int* src = ei;
    const int* dst = ei + NE;
    float* out = (float*)d_out;

    char* ws = (char*)d_ws;
    size_t o = 0;
    int*     deg       = (int*)(ws + o);     o += (size_t)NN * 4;
    int*     row_start = (int*)(ws + o);     o += (size_t)NN * 4;
    float*   dinv      = (float*)(ws + o);   o += (size_t)NN * 4;
    int*     hist      = (int*)(ws + o);     o += (size_t)M1 * 4;
    int*     hist_scan = (int*)(ws + o);     o += (size_t)M1 * 4;
    int*     partials  = (int*)(ws + o);     o += 128 * 4;
    int*     csr       = (int*)(ws + o);     o += (size_t)CSR_CAP * 4;         // 14MB pad-4 CSR
    __half*  A         = (__half*)(ws + o);  o += (size_t)(NN + 1) * PAD * 2;  // 12.8MB
    __half2* Rh        = (__half2*)(ws + o); o += (size_t)NN * 24 * 4;         // 9.6MB fp16 R
    __half*  B         = (__half*)(ws + o);  o += (size_t)(NN + 1) * PAD * 2;  // 12.8MB
    float*   wT        = (float*)(ws + o);   o += 96 * 68 * 4;                 // 26KB transposed weights
    // overlays
    int*    recs  = (int*)A;                 // NE*4 = 12.8MB fits in A region; dead before t1
    __half* L1f   = A;                       // spmm48#2 output (reads B, not A)
    float*  A2    = (float*)Rh;              // layer-2 buffers live in Rh (dead after spmm48#2)
    float*  R2    = (float*)Rh + (size_t)NN * KO;
    float*  C2    = (float*)Rh + (size_t)NN * KO * 2;   // 7.2MB <= 9.6MB

    // ---- CSR build (5 dispatches) ----
    k_hist       <<<PB, 256, 0, stream>>>(dst, hist);
    k_partial    <<<NSCB, 256, 0, stream>>>(hist, partials, M1);
    k_downsweepF <<<NSCB, 256, 0, stream>>>(hist, partials, hist_scan, M1);
    k_pass2      <<<PB, 256, 0, stream>>>(src, dst, hist_scan, recs);
    k_degsort    <<<NBINS, BINW, 0, stream>>>(recs, hist_scan, deg, dinv, row_start, csr);

    // ---- layer 1 ----
    k_wprep <<<1, 256, 0, stream>>>(iw1, rw1, wT, (__half2*)A, (__half2*)B);
    k_t1    <<<dim3(T1B, 2), 256, 0, stream>>>(x, wT, b1, dinv, (__half2*)A, Rh);
    k_spmm48<true>  <<<NN / 4, 256, 0, stream>>>((const f16x2*)A, Rh, row_start, deg, dinv, csr, w1, (__half2*)B);
    k_spmm48<false> <<<NN / 4, 256, 0, stream>>>((const f16x2*)B, Rh, row_start, deg, dinv, csr, w1, (__half2*)L1f);

    // ---- layer 2 ----
    k_mt2     <<<(NN + 255) / 256, 256, 0, stream>>>(L1f, iw2, rw2, b2, dinv, A2, R2);
    k_spmm6_g <<<(NN * KO + 255) / 256, 256, 0, stream>>>(A2, R2, row_start, deg, dinv, csr, w2, C2);
    k_spmm6_f <<<NN / 40, 256, 0, stream>>>(C2, R2, row_start, deg, dinv, csr, out);
}

// Round 13
// 301.547 us; speedup vs baseline: 1.4367x; 1.0345x over previous
//
#include <hip/hip_runtime.h>
#include <hip/hip_fp16.h>
#include <math.h>

#define NN 100000
#define NE 3200000
#define FEA 67
#define HID 16
#define OUTC 2
#define KS 3
#define KH 48   /* KS*HID */
#define KO 6    /* KS*OUTC */
#define PAD 64  /* padded fp16 row stride: 128B = 1 cache line */

#define PB 512          /* partition blocks */
#define EPB 6250        /* edges per partition block (PB*EPB == NE) */
#define BINW 512        /* nodes per bin */
#define NBINS 196       /* ceil(NN/BINW) */
#define M1 (NBINS * PB) /* 100352 */
#define NSCB 98         /* scan blocks: 98*1024 == M1 exactly */
#define CSR_CAP (NE + NBINS * 3 * BINW + 64)   /* pad-4 CSR capacity */

#define T1B 1563        /* t1 blocks per half: 1563*64 >= NN */

typedef _Float16 f16x2 __attribute__((ext_vector_type(2)));

// ---------------- partition: histogram ----------------

__global__ void k_hist(const int* __restrict__ dst, int* __restrict__ hist) {
    __shared__ int h[NBINS];
    if (threadIdx.x < NBINS) h[threadIdx.x] = 0;
    __syncthreads();
    int base = blockIdx.x * EPB;
    for (int i = threadIdx.x; i < EPB; i += 256)
        atomicAdd(&h[dst[base + i] >> 9], 1);
    __syncthreads();
    if (threadIdx.x < NBINS) hist[threadIdx.x * PB + blockIdx.x] = h[threadIdx.x];
}

// ---------------- 2-kernel exclusive scan ----------------

__global__ void k_partial(const int* __restrict__ in, int* __restrict__ partials, int n) {
    __shared__ int s[256];
    int base = blockIdx.x * 1024;
    int acc = 0;
    for (int i = threadIdx.x; i < 1024; i += 256) {
        int idx = base + i;
        if (idx < n) acc += in[idx];
    }
    s[threadIdx.x] = acc;
    __syncthreads();
    for (int off = 128; off > 0; off >>= 1) {
        if (threadIdx.x < off) s[threadIdx.x] += s[threadIdx.x + off];
        __syncthreads();
    }
    if (threadIdx.x == 0) partials[blockIdx.x] = s[0];
}

__global__ void k_downsweepF(const int* __restrict__ in, const int* __restrict__ partials,
                             int* __restrict__ out, int n) {
    __shared__ int ps[256];
    __shared__ int s[256];
    int t = threadIdx.x;
    ps[t] = (t < NSCB) ? partials[t] : 0;
    __syncthreads();
    for (int off = 1; off < 256; off <<= 1) {
        int v = (t >= off) ? ps[t - off] : 0;
        __syncthreads();
        ps[t] += v;
        __syncthreads();
    }
    int bbase = (blockIdx.x > 0) ? ps[blockIdx.x - 1] : 0;

    int base = blockIdx.x * 1024 + t * 4;
    int d0 = 0, d1 = 0, d2 = 0, d3 = 0;
    if (base + 0 < n) d0 = in[base + 0];
    if (base + 1 < n) d1 = in[base + 1];
    if (base + 2 < n) d2 = in[base + 2];
    if (base + 3 < n) d3 = in[base + 3];
    int ts = d0 + d1 + d2 + d3;
    s[t] = ts;
    __syncthreads();
    for (int off = 1; off < 256; off <<= 1) {
        int v = (t >= off) ? s[t - off] : 0;
        __syncthreads();
        s[t] += v;
        __syncthreads();
    }
    int excl = s[t] - ts + bbase;
    if (base + 0 < n) out[base + 0] = excl;
    if (base + 1 < n) out[base + 1] = excl + d0;
    if (base + 2 < n) out[base + 2] = excl + d0 + d1;
    if (base + 3 < n) out[base + 3] = excl + d0 + d1 + d2;
}

// ---------------- partition: scatter to bins ----------------

__global__ void k_pass2(const int* __restrict__ src, const int* __restrict__ dst,
                        const int* __restrict__ hist_scan, int* __restrict__ recs) {
    __shared__ int curs[NBINS];
    if (threadIdx.x < NBINS) curs[threadIdx.x] = hist_scan[threadIdx.x * PB + blockIdx.x];
    __syncthreads();
    int base = blockIdx.x * EPB;
    for (int i = threadIdx.x; i < EPB; i += 256) {
        int e = base + i;
        int s = src[e], d = dst[e];
        int pos = atomicAdd(&curs[d >> 9], 1);
        recs[pos] = s | ((d & 511) << 17);            // src:17b | dst_local:9b
    }
}

// ---------------- fused per-bin: degree + dinv + pad-4 row_start + CSR scatter ----------------

__global__ void k_degsort(const int* __restrict__ recs, const int* __restrict__ hist_scan,
                          int* __restrict__ deg, float* __restrict__ dinv,
                          int* __restrict__ row_start, int* __restrict__ csr) {
    __shared__ int cnt[BINW];
    __shared__ int scn[BINW];
    int bin = blockIdx.x, t = threadIdx.x;
    cnt[t] = 0;
    __syncthreads();
    int s0 = hist_scan[bin * PB];
    int s1 = (bin + 1 < NBINS) ? hist_scan[(bin + 1) * PB] : NE;
    for (int r = s0 + t; r < s1; r += BINW)
        atomicAdd(&cnt[((unsigned)recs[r]) >> 17], 1);
    __syncthreads();
    int c  = cnt[t];
    int c4 = (c + 3) & ~3;
    scn[t] = c4;
    __syncthreads();
    for (int off = 1; off < BINW; off <<= 1) {
        int v = (t >= off) ? scn[t - off] : 0;
        __syncthreads();
        scn[t] += v;
        __syncthreads();
    }
    int base = s0 + bin * (3 * BINW);      // pad-4 region base for this bin
    int rs   = base + scn[t] - c4;         // exclusive padded prefix
    int node = bin * BINW + t;
    if (node < NN) {
        deg[node]       = c;
        dinv[node]      = (c > 0) ? rsqrtf((float)c) : 0.f;
        row_start[node] = rs;
    }
    scn[t] = rs;                            // scatter cursor
    __syncthreads();
    for (int r = s0 + t; r < s1; r += BINW) {
        int rec = recs[r];
        int pos = atomicAdd(&scn[((unsigned)rec) >> 17], 1);
        csr[pos] = rec & 0x1FFFF;
    }
    __syncthreads();
    int e4 = rs + c4;
    for (int i = scn[t]; i < e4; ++i) csr[i] = NN;   // sentinel pads (zero row)
}

// ---------------- weight prep: transpose iw/rw -> wT[96][68]; zero A/B pad rows ----------------

__global__ void k_wprep(const float* __restrict__ iw, const float* __restrict__ rw,
                        float* __restrict__ wT, __half2* __restrict__ Ah, __half2* __restrict__ Bh) {
    int t = threadIdx.x;
    __half2 z = __halves2half2(__float2half(0.f), __float2half(0.f));
    if (t < 32)      Ah[(size_t)NN * 32 + t] = z;          // zero pad row NN of A
    else if (t < 64) Bh[(size_t)NN * 32 + (t - 32)] = z;   // zero pad row NN of B
    for (int idx = t; idx < KS * FEA * HID; idx += 256) {
        int k = idx / (FEA * HID);
        int r = idx - k * (FEA * HID);
        int f = r >> 4, h = r & 15;
        int j = k * 16 + h;
        float vi = iw[idx], vr = rw[idx];
        wT[j * 68 + f]        = vi;
        wT[(48 + j) * 68 + f] = vr;
    }
}

// ---------------- layer 1 dense transform: 64 nodes/block, half-split ----------------

__global__ void k_t1(const float* __restrict__ x, const float* __restrict__ wT,
                     const float* __restrict__ b1, const float* __restrict__ dinv,
                     __half2* __restrict__ Ah, __half2* __restrict__ Rh) {
    __shared__ float xs[64 * 68];    // 17408 B
    __shared__ float wls[48 * 68];   // 13056 B
    __shared__ float bbs[48];
    int half = blockIdx.y;
    int n0   = blockIdx.x * 64;
    const float* wsrc = wT + half * (48 * 68);
    for (int idx = threadIdx.x; idx < 48 * 68; idx += 256) wls[idx] = wsrc[idx];
    int lim = (NN - n0) * FEA;       // exact readable extent of this tile
    for (int idx = threadIdx.x; idx < 64 * FEA; idx += 256) {
        int nl = idx / FEA, f = idx - nl * FEA;
        xs[nl * 68 + f] = (idx < lim) ? x[(size_t)n0 * FEA + idx] : 0.f;
    }
    if (half && threadIdx.x < 48) bbs[threadIdx.x] = b1[threadIdx.x];
    __syncthreads();

    int nl = threadIdx.x >> 2, cg = threadIdx.x & 3;
    int n  = n0 + nl;
    float acc[12];
    #pragma unroll
    for (int p = 0; p < 12; ++p) acc[p] = 0.f;
    if (half) {
        #pragma unroll
        for (int p = 0; p < 12; ++p) acc[p] = bbs[cg * 12 + p];
    }
    const float* xr = &xs[nl * 68];
    const float* wb = &wls[cg * 12 * 68];
    #pragma unroll 4
    for (int fb = 0; fb < 16; ++fb) {
        int f0 = fb * 4;
        float4 xv = *(const float4*)&xr[f0];
        #pragma unroll
        for (int p = 0; p < 12; ++p) {
            float4 wv = *(const float4*)&wb[p * 68 + f0];
            acc[p] += xv.x * wv.x + xv.y * wv.y + xv.z * wv.z + xv.w * wv.w;
        }
    }
    #pragma unroll
    for (int f = 64; f < FEA; ++f) {
        float xv = xr[f];
        #pragma unroll
        for (int p = 0; p < 12; ++p) acc[p] += xv * wb[p * 68 + f];
    }

    if (n < NN) {
        if (half == 0) {
            float dv = dinv[n];
            #pragma unroll
            for (int p2 = 0; p2 < 6; ++p2)
                Ah[(size_t)n * 32 + cg * 6 + p2] =
                    __halves2half2(__float2half_rn(acc[2 * p2] * dv),
                                   __float2half_rn(acc[2 * p2 + 1] * dv));
        } else {
            #pragma unroll
            for (int p2 = 0; p2 < 6; ++p2)
                Rh[(size_t)n * 24 + cg * 6 + p2] =
                    __halves2half2(__float2half_rn(acc[2 * p2]),
                                   __float2half_rn(acc[2 * p2 + 1]));
        }
    }
}

// ---------------- SpMM 48-wide: pair scheme, predicated chunk stage + split fdot2 chains ----------------

template <bool FUSEW>
__global__ void k_spmm48(const f16x2* __restrict__ Asrc,    // row stride 32 f16x2
                         const __half2* __restrict__ Rh,    // row stride 24 half2
                         const int* __restrict__ row_start, const int* __restrict__ deg,
                         const float* __restrict__ dinv, const int* __restrict__ csr,
                         const float* __restrict__ w1, __half2* __restrict__ Bout) {
    __shared__ float w1s[FUSEW ? KS * HID * HID : 1];
    __shared__ int chunk[4][64];
    if (FUSEW) {
        for (int i = threadIdx.x; i < KS * HID * HID; i += 256) w1s[i] = w1[i];
        __syncthreads();
    }
    int wv   = threadIdx.x >> 6;
    int node = (blockIdx.x * 256 + threadIdx.x) >> 6;   // one wave per node
    int lane = threadIdx.x & 63;
    int eo   = lane >> 5;           // edge parity within pair
    int cl   = lane & 31;           // col-pair index (cols 2cl, 2cl+1)
    int start = __builtin_amdgcn_readfirstlane(row_start[node]);
    int d     = __builtin_amdgcn_readfirstlane(deg[node]);
    int d4    = (d + 3) & ~3;       // csr padded with NN sentinels (zero row)
    float dv  = dinv[node];
    float2 r2 = make_float2(0.f, 0.f);
    if (cl < 24) r2 = __half22float2(Rh[(size_t)node * 24 + cl]);

    f16x2 h10 = {(_Float16)1.f, (_Float16)0.f};
    f16x2 h01 = {(_Float16)0.f, (_Float16)1.f};
    int* ch = &chunk[wv][0];
    const int* cp = ch + eo;        // read base: +eo*4 bytes; pair p at offset 8p
    float ax0 = 0.f, ay0 = 0.f, ax1 = 0.f, ay1 = 0.f;
    for (int b = 0; b < d4; b += 64) {
        int nb = min(64, d4 - b);               // multiple of 4
        if (lane < nb) ch[lane] = csr[start + b + lane];   // predicated: no CSR overfetch
        int npf = nb >> 1;                      // pairs, multiple of 2
        int p = 0;
        for (; p + 4 <= npf; p += 4) {
            unsigned c0 = (unsigned)cp[2 * (p + 0)];
            unsigned c1 = (unsigned)cp[2 * (p + 1)];
            unsigned c2 = (unsigned)cp[2 * (p + 2)];
            unsigned c3 = (unsigned)cp[2 * (p + 3)];
            f16x2 f0 = Asrc[c0 * 32u + (unsigned)cl];
            f16x2 f1 = Asrc[c1 * 32u + (unsigned)cl];
            f16x2 f2 = Asrc[c2 * 32u + (unsigned)cl];
            f16x2 f3 = Asrc[c3 * 32u + (unsigned)cl];
            // two independent accumulation chains per component
            ax0 = __builtin_amdgcn_fdot2(f0, h10, ax0, false);
            ay0 = __builtin_amdgcn_fdot2(f0, h01, ay0, false);
            ax1 = __builtin_amdgcn_fdot2(f1, h10, ax1, false);
            ay1 = __builtin_amdgcn_fdot2(f1, h01, ay1, false);
            ax0 = __builtin_amdgcn_fdot2(f2, h10, ax0, false);
            ay0 = __builtin_amdgcn_fdot2(f2, h01, ay0, false);
            ax1 = __builtin_amdgcn_fdot2(f3, h10, ax1, false);
            ay1 = __builtin_amdgcn_fdot2(f3, h01, ay1, false);
        }
        for (; p < npf; ++p) {
            unsigned c = (unsigned)cp[2 * p];
            f16x2 f = Asrc[c * 32u + (unsigned)cl];
            ax0 = __builtin_amdgcn_fdot2(f, h10, ax0, false);
            ay0 = __builtin_amdgcn_fdot2(f, h01, ay0, false);
        }
    }
    float ax = ax0 + ax1;
    float ay = ay0 + ay1;
    // combine edge parities
    ax += __shfl_xor(ax, 32, 64);
    ay += __shfl_xor(ay, 32, 64);
    // root + relu (both layer-1 propagates end in relu)
    float vx = fmaxf(ax * dv + r2.x, 0.f);
    float vy = fmaxf(ay * dv + r2.y, 0.f);

    if (FUSEW) {
        // out[k*16+p0], out[k*16+p0+1] = sum_h in[k*16+h] * w1[k][h][p]
        int k  = cl >> 3;              // (2cl)>>4
        int p0 = (2 * cl) & 15;
        float o0 = 0.f, o1 = 0.f;
        #pragma unroll
        for (int h2 = 0; h2 < 8; ++h2) {
            float ix = __shfl(vx, k * 8 + h2, 64);   // in[k*16 + 2h2]
            float iy = __shfl(vy, k * 8 + h2, 64);   // in[k*16 + 2h2+1]
            o0 += ix * w1s[k * 256 + (2 * h2) * 16 + p0]     + iy * w1s[k * 256 + (2 * h2 + 1) * 16 + p0];
            o1 += ix * w1s[k * 256 + (2 * h2) * 16 + p0 + 1] + iy * w1s[k * 256 + (2 * h2 + 1) * 16 + p0 + 1];
        }
        if (eo == 0 && cl < 24)
            Bout[(size_t)node * (PAD / 2) + cl] =
                __halves2half2(__float2half_rn(o0 * dv), __float2half_rn(o1 * dv));
    } else {
        if (eo == 0 && cl < 24)
            Bout[(size_t)node * (PAD / 2) + cl] =
                __halves2half2(__float2half_rn(vx), __float2half_rn(vy));
    }
}

// ---------------- fused mean+relu+transform2 ----------------

__global__ void k_mt2(const __half* __restrict__ L1, const float* __restrict__ iw,
                      const float* __restrict__ rw, const float* __restrict__ b2,
                      const float* __restrict__ dinv,
                      float* __restrict__ A2, float* __restrict__ R2) {
    __shared__ float wi[KS * HID * OUTC];
    __shared__ float wr_[KS * HID * OUTC];
    __shared__ float bb[KO];
    if (threadIdx.x < KS * HID * OUTC) { wi[threadIdx.x] = iw[threadIdx.x]; wr_[threadIdx.x] = rw[threadIdx.x]; }
    if (threadIdx.x < KO) bb[threadIdx.x] = b2[threadIdx.x];
    __syncthreads();
    int n = blockIdx.x * 256 + threadIdx.x;
    if (n >= NN) return;
    const __half2* hp = (const __half2*)(L1 + (size_t)n * PAD);
    float v[KH];
    #pragma unroll
    for (int q = 0; q < 24; ++q) {
        float2 f = __half22float2(hp[q]);
        v[q * 2 + 0] = f.x; v[q * 2 + 1] = f.y;
    }
    float h[HID];
    #pragma unroll
    for (int hh = 0; hh < HID; ++hh)
        h[hh] = fmaxf((v[hh] + v[16 + hh] + v[32 + hh]) * (1.f / 3.f), 0.f);
    float dv = dinv[n];
    #pragma unroll
    for (int k = 0; k < KS; ++k) {
        #pragma unroll
        for (int o = 0; o < OUTC; ++o) {
            float a = 0.f, r = bb[k * 2 + o];
            #pragma unroll
            for (int hh = 0; hh < HID; ++hh) {
                a += h[hh] * wi[k * 32 + hh * 2 + o];
                r += h[hh] * wr_[k * 32 + hh * 2 + o];
            }
            A2[n * KO + k * 2 + o] = a * dv;
            R2[n * KO + k * 2 + o] = r;
        }
    }
}

// ---------------- SpMM 6-wide #1: fused 2x2 gemm (w2), output pre-scaled ----------------

__global__ void k_spmm6_g(const float* __restrict__ Asrc, const float* __restrict__ R2,
                          const int* __restrict__ row_start, const int* __restrict__ deg,
                          const float* __restrict__ dinv, const int* __restrict__ csr,
                          const float* __restrict__ w2, float* __restrict__ Bout) {
    __shared__ float ws[KS * OUTC * OUTC];
    if (threadIdx.x < KS * OUTC * OUTC) ws[threadIdx.x] = w2[threadIdx.x];
    __syncthreads();
    int t = blockIdx.x * 256 + threadIdx.x;
    int node = t / KO, j = t % KO;
    bool active = node < NN;
    float acc = 0.f, r = 0.f, dv = 0.f;
    int start = 0, d = 0;
    if (active) {
        start = row_start[node];
        d     = deg[node];
        r     = R2[node * KO + j];
        dv    = dinv[node];
    }
    int e = 0;
    for (; e + 4 <= d; e += 4) {
        int c0 = csr[start + e + 0];
        int c1 = csr[start + e + 1];
        int c2 = csr[start + e + 2];
        int c3 = csr[start + e + 3];
        acc += Asrc[c0 * KO + j];
        acc += Asrc[c1 * KO + j];
        acc += Asrc[c2 * KO + j];
        acc += Asrc[c3 * KO + j];
    }
    for (; e < d; ++e)
        acc += Asrc[csr[start + e] * KO + j];
    float v = acc * dv + r;
    float other = __shfl_xor(v, 1, 64);
    if (active) {
        int k = j >> 1, p = j & 1;
        float v0 = (p == 0) ? v : other;
        float v1 = (p == 0) ? other : v;
        Bout[node * KO + j] = (v0 * ws[k * 4 + p] + v1 * ws[k * 4 + 2 + p]) * dv;
    }
}

// ---------------- SpMM 6-wide #2: fused mean + log_softmax (10 nodes/wave) ----------------

__global__ void k_spmm6_f(const float* __restrict__ Asrc, const float* __restrict__ R2,
                          const int* __restrict__ row_start, const int* __restrict__ deg,
                          const float* __restrict__ dinv, const int* __restrict__ csr,
                          float* __restrict__ out) {
    int wave = threadIdx.x >> 6;
    int l    = threadIdx.x & 63;
    int nl   = l / 6;            // 0..10 (10 = inactive)
    int j    = l - nl * 6;
    bool active = nl < 10;
    int node = blockIdx.x * 40 + wave * 10 + nl;
    float acc = 0.f, r = 0.f, dv = 0.f;
    int start = 0, d = 0;
    if (active) {
        start = row_start[node];
        d     = deg[node];
        r     = R2[node * KO + j];
        dv    = dinv[node];
    }
    int e = 0;
    for (; e + 4 <= d; e += 4) {
        int c0 = csr[start + e + 0];
        int c1 = csr[start + e + 1];
        int c2 = csr[start + e + 2];
        int c3 = csr[start + e + 3];
        acc += Asrc[c0 * KO + j];
        acc += Asrc[c1 * KO + j];
        acc += Asrc[c2 * KO + j];
        acc += Asrc[c3 * KO + j];
    }
    for (; e < d; ++e)
        acc += Asrc[csr[start + e] * KO + j];
    float v = acc * dv + r;
    int base = nl * 6;
    float o0 = (__shfl(v, base + 0, 64) + __shfl(v, base + 2, 64) + __shfl(v, base + 4, 64)) * (1.f / 3.f);
    float o1 = (__shfl(v, base + 1, 64) + __shfl(v, base + 3, 64) + __shfl(v, base + 5, 64)) * (1.f / 3.f);
    if (active && j == 0) {
        float m = fmaxf(o0, o1);
        float ls = m + logf(expf(o0 - m) + expf(o1 - m));
        *(float2*)(out + (size_t)node * 2) = make_float2(o0 - ls, o1 - ls);
    }
}

// ---------------- host ----------------

extern "C" void kernel_launch(void* const* d_in, const int* in_sizes, int n_in,
                              void* d_out, int out_size, void* d_ws, size_t ws_size,
                              hipStream_t stream) {
    const float* x   = (const float*)d_in[0];
    const int*   ei  = (const int*)d_in[1];
    const float* iw1 = (const float*)d_in[2];
    const float* w1  = (const float*)d_in[3];
    const float* rw1 = (const float*)d_in[4];
    const float* b1  = (const float*)d_in[5];
    const float* iw2 = (const float*)d_in[6];
    const float* w2  = (const float*)d_in[7];
    const float* rw2 = (const float*)d_in[8];
    const float* b2  = (const float*)d_in[9];
    const int* src = ei;
    const int* dst = ei + NE;
    float* out = (float*)d_out;

    char* ws = (char*)d_ws;
    size_t o = 0;
    int*     deg       = (int*)(ws + o);     o += (size_t)NN * 4;
    int*     row_start = (int*)(ws + o);     o += (size_t)NN * 4;
    float*   dinv      = (float*)(ws + o);   o += (size_t)NN * 4;
    int*     hist      = (int*)(ws + o);     o += (size_t)M1 * 4;
    int*     hist_scan = (int*)(ws + o);     o += (size_t)M1 * 4;
    int*     partials  = (int*)(ws + o);     o += 128 * 4;
    int*     csr       = (int*)(ws + o);     o += (size_t)CSR_CAP * 4;         // 14MB pad-4 CSR
    __half*  A         = (__half*)(ws + o);  o += (size_t)(NN + 1) * PAD * 2;  // 12.8MB
    __half2* Rh        = (__half2*)(ws + o); o += (size_t)NN * 24 * 4;         // 9.6MB fp16 R
    __half*  B         = (__half*)(ws + o);  o += (size_t)(NN + 1) * PAD * 2;  // 12.8MB
    float*   wT        = (float*)(ws + o);   o += 96 * 68 * 4;                 // 26KB transposed weights
    // overlays
    int*    recs  = (int*)A;                 // NE*4 = 12.8MB fits in A region; dead before t1
    __half* L1f   = A;                       // spmm48#2 output (reads B, not A)
    float*  A2    = (float*)Rh;              // layer-2 buffers live in Rh (dead after spmm48#2)
    float*  R2    = (float*)Rh + (size_t)NN * KO;
    float*  C2    = (float*)Rh + (size_t)NN * KO * 2;   // 7.2MB <= 9.6MB

    // ---- CSR build (5 dispatches) ----
    k_hist       <<<PB, 256, 0, stream>>>(dst, hist);
    k_partial    <<<NSCB, 256, 0, stream>>>(hist, partials, M1);
    k_downsweepF <<<NSCB, 256, 0, stream>>>(hist, partials, hist_scan, M1);
    k_pass2      <<<PB, 256, 0, stream>>>(src, dst, hist_scan, recs);
    k_degsort    <<<NBINS, BINW, 0, stream>>>(recs, hist_scan, deg, dinv, row_start, csr);

    // ---- layer 1 ----
    k_wprep <<<1, 256, 0, stream>>>(iw1, rw1, wT, (__half2*)A, (__half2*)B);
    k_t1    <<<dim3(T1B, 2), 256, 0, stream>>>(x, wT, b1, dinv, (__half2*)A, Rh);
    k_spmm48<true>  <<<NN / 4, 256, 0, stream>>>((const f16x2*)A, Rh, row_start, deg, dinv, csr, w1, (__half2*)B);
    k_spmm48<false> <<<NN / 4, 256, 0, stream>>>((const f16x2*)B, Rh, row_start, deg, dinv, csr, w1, (__half2*)L1f);

    // ---- layer 2 ----
    k_mt2     <<<(NN + 255) / 256, 256, 0, stream>>>(L1f, iw2, rw2, b2, dinv, A2, R2);
    k_spmm6_g <<<(NN * KO + 255) / 256, 256, 0, stream>>>(A2, R2, row_start, deg, dinv, csr, w2, C2);
    k_spmm6_f <<<NN / 40, 256, 0, stream>>>(C2, R2, row_start, deg, dinv, csr, out);
}

// Round 14
// 295.686 us; speedup vs baseline: 1.4652x; 1.0198x over previous
//
#include <hip/hip_runtime.h>
#include <hip/hip_fp16.h>
#include <math.h>

#define NN 100000
#define NE 3200000
#define FEA 67
#define HID 16
#define OUTC 2
#define KS 3
#define KH 48   /* KS*HID */
#define KO 6    /* KS*OUTC */
#define PAD 64  /* padded fp16 row stride: 128B = 1 cache line */

#define PB 512          /* partition blocks */
#define EPB 6250        /* edges per partition block (PB*EPB == NE) */
#define BINW 512        /* nodes per bin */
#define NBINS 196       /* ceil(NN/BINW) */
#define M1 (NBINS * PB) /* 100352 */
#define NSCB 98         /* scan blocks: 98*1024 == M1 exactly */
#define CSR_CAP (NE + NBINS * 3 * BINW + 64)   /* pad-4 CSR capacity */

#define T1B 1563        /* t1 blocks per half: 1563*64 >= NN */

typedef _Float16 f16x2 __attribute__((ext_vector_type(2)));

// ---------------- partition: histogram ----------------

__global__ void k_hist(const int* __restrict__ dst, int* __restrict__ hist) {
    __shared__ int h[NBINS];
    if (threadIdx.x < NBINS) h[threadIdx.x] = 0;
    __syncthreads();
    int base = blockIdx.x * EPB;
    for (int i = threadIdx.x; i < EPB; i += 256)
        atomicAdd(&h[dst[base + i] >> 9], 1);
    __syncthreads();
    if (threadIdx.x < NBINS) hist[threadIdx.x * PB + blockIdx.x] = h[threadIdx.x];
}

// ---------------- 2-kernel exclusive scan ----------------

__global__ void k_partial(const int* __restrict__ in, int* __restrict__ partials, int n) {
    __shared__ int s[256];
    int base = blockIdx.x * 1024;
    int acc = 0;
    for (int i = threadIdx.x; i < 1024; i += 256) {
        int idx = base + i;
        if (idx < n) acc += in[idx];
    }
    s[threadIdx.x] = acc;
    __syncthreads();
    for (int off = 128; off > 0; off >>= 1) {
        if (threadIdx.x < off) s[threadIdx.x] += s[threadIdx.x + off];
        __syncthreads();
    }
    if (threadIdx.x == 0) partials[blockIdx.x] = s[0];
}

__global__ void k_downsweepF(const int* __restrict__ in, const int* __restrict__ partials,
                             int* __restrict__ out, int n) {
    __shared__ int ps[256];
    __shared__ int s[256];
    int t = threadIdx.x;
    ps[t] = (t < NSCB) ? partials[t] : 0;
    __syncthreads();
    for (int off = 1; off < 256; off <<= 1) {
        int v = (t >= off) ? ps[t - off] : 0;
        __syncthreads();
        ps[t] += v;
        __syncthreads();
    }
    int bbase = (blockIdx.x > 0) ? ps[blockIdx.x - 1] : 0;

    int base = blockIdx.x * 1024 + t * 4;
    int d0 = 0, d1 = 0, d2 = 0, d3 = 0;
    if (base + 0 < n) d0 = in[base + 0];
    if (base + 1 < n) d1 = in[base + 1];
    if (base + 2 < n) d2 = in[base + 2];
    if (base + 3 < n) d3 = in[base + 3];
    int ts = d0 + d1 + d2 + d3;
    s[t] = ts;
    __syncthreads();
    for (int off = 1; off < 256; off <<= 1) {
        int v = (t >= off) ? s[t - off] : 0;
        __syncthreads();
        s[t] += v;
        __syncthreads();
    }
    int excl = s[t] - ts + bbase;
    if (base + 0 < n) out[base + 0] = excl;
    if (base + 1 < n) out[base + 1] = excl + d0;
    if (base + 2 < n) out[base + 2] = excl + d0 + d1;
    if (base + 3 < n) out[base + 3] = excl + d0 + d1 + d2;
}

// ---------------- partition: scatter to bins ----------------

__global__ void k_pass2(const int* __restrict__ src, const int* __restrict__ dst,
                        const int* __restrict__ hist_scan, int* __restrict__ recs) {
    __shared__ int curs[NBINS];
    if (threadIdx.x < NBINS) curs[threadIdx.x] = hist_scan[threadIdx.x * PB + blockIdx.x];
    __syncthreads();
    int base = blockIdx.x * EPB;
    for (int i = threadIdx.x; i < EPB; i += 256) {
        int e = base + i;
        int s = src[e], d = dst[e];
        int pos = atomicAdd(&curs[d >> 9], 1);
        recs[pos] = s | ((d & 511) << 17);            // src:17b | dst_local:9b
    }
}

// ---------------- fused per-bin: degree + dinv + pad-4 row_start + CSR scatter ----------------
// 1024 threads/block: 196 blocks are occupancy-starved at 512 (sub-1 block/CU).

__global__ void k_degsort(const int* __restrict__ recs, const int* __restrict__ hist_scan,
                          int* __restrict__ deg, float* __restrict__ dinv,
                          int* __restrict__ row_start, int* __restrict__ csr) {
    __shared__ int cnt[BINW];
    __shared__ int scn[BINW];
    int bin = blockIdx.x, t = threadIdx.x;
    if (t < BINW) cnt[t] = 0;
    __syncthreads();
    int s0 = hist_scan[bin * PB];
    int s1 = (bin + 1 < NBINS) ? hist_scan[(bin + 1) * PB] : NE;
    for (int r = s0 + t; r < s1; r += 1024)
        atomicAdd(&cnt[((unsigned)recs[r]) >> 17], 1);
    __syncthreads();
    if (t < BINW) scn[t] = (cnt[t] + 3) & ~3;
    __syncthreads();
    for (int off = 1; off < BINW; off <<= 1) {
        int v = (t < BINW && t >= off) ? scn[t - off] : 0;
        __syncthreads();
        if (t < BINW) scn[t] += v;
        __syncthreads();
    }
    int base = s0 + bin * (3 * BINW);      // pad-4 region base for this bin
    int rs = 0, c4 = 0;
    if (t < BINW) {
        int c = cnt[t];
        c4 = (c + 3) & ~3;
        rs = base + scn[t] - c4;           // exclusive padded prefix
        int node = bin * BINW + t;
        if (node < NN) {
            deg[node]       = c;
            dinv[node]      = (c > 0) ? rsqrtf((float)c) : 0.f;
            row_start[node] = rs;
        }
    }
    __syncthreads();
    if (t < BINW) scn[t] = rs;             // scatter cursor
    __syncthreads();
    for (int r = s0 + t; r < s1; r += 1024) {
        int rec = recs[r];
        int pos = atomicAdd(&scn[((unsigned)rec) >> 17], 1);
        csr[pos] = rec & 0x1FFFF;
    }
    __syncthreads();
    if (t < BINW) {
        int e4 = rs + c4;
        for (int i = scn[t]; i < e4; ++i) csr[i] = NN;   // sentinel pads (zero row)
    }
}

// ---------------- weight prep: transpose iw/rw -> wT[96][68]; zero A/B pad rows ----------------

__global__ void k_wprep(const float* __restrict__ iw, const float* __restrict__ rw,
                        float* __restrict__ wT, __half2* __restrict__ Ah, __half2* __restrict__ Bh) {
    int t = threadIdx.x;
    __half2 z = __halves2half2(__float2half(0.f), __float2half(0.f));
    if (t < 32)      Ah[(size_t)NN * 32 + t] = z;          // zero pad row NN of A
    else if (t < 64) Bh[(size_t)NN * 32 + (t - 32)] = z;   // zero pad row NN of B
    for (int idx = t; idx < KS * FEA * HID; idx += 256) {
        int k = idx / (FEA * HID);
        int r = idx - k * (FEA * HID);
        int f = r >> 4, h = r & 15;
        int j = k * 16 + h;
        float vi = iw[idx], vr = rw[idx];
        wT[j * 68 + f]        = vi;
        wT[(48 + j) * 68 + f] = vr;
    }
}

// ---------------- layer 1 dense transform: 64 nodes/block, half-split ----------------

__global__ void k_t1(const float* __restrict__ x, const float* __restrict__ wT,
                     const float* __restrict__ b1, const float* __restrict__ dinv,
                     __half2* __restrict__ Ah, __half2* __restrict__ Rh) {
    __shared__ float xs[64 * 68];    // 17408 B
    __shared__ float wls[48 * 68];   // 13056 B
    __shared__ float bbs[48];
    int half = blockIdx.y;
    int n0   = blockIdx.x * 64;
    const float* wsrc = wT + half * (48 * 68);
    for (int idx = threadIdx.x; idx < 48 * 68; idx += 256) wls[idx] = wsrc[idx];
    int lim = (NN - n0) * FEA;       // exact readable extent of this tile
    for (int idx = threadIdx.x; idx < 64 * FEA; idx += 256) {
        int nl = idx / FEA, f = idx - nl * FEA;
        xs[nl * 68 + f] = (idx < lim) ? x[(size_t)n0 * FEA + idx] : 0.f;
    }
    if (half && threadIdx.x < 48) bbs[threadIdx.x] = b1[threadIdx.x];
    __syncthreads();

    int nl = threadIdx.x >> 2, cg = threadIdx.x & 3;
    int n  = n0 + nl;
    float acc[12];
    #pragma unroll
    for (int p = 0; p < 12; ++p) acc[p] = 0.f;
    if (half) {
        #pragma unroll
        for (int p = 0; p < 12; ++p) acc[p] = bbs[cg * 12 + p];
    }
    const float* xr = &xs[nl * 68];
    const float* wb = &wls[cg * 12 * 68];
    #pragma unroll 4
    for (int fb = 0; fb < 16; ++fb) {
        int f0 = fb * 4;
        float4 xv = *(const float4*)&xr[f0];
        #pragma unroll
        for (int p = 0; p < 12; ++p) {
            float4 wv = *(const float4*)&wb[p * 68 + f0];
            acc[p] += xv.x * wv.x + xv.y * wv.y + xv.z * wv.z + xv.w * wv.w;
        }
    }
    #pragma unroll
    for (int f = 64; f < FEA; ++f) {
        float xv = xr[f];
        #pragma unroll
        for (int p = 0; p < 12; ++p) acc[p] += xv * wb[p * 68 + f];
    }

    if (n < NN) {
        if (half == 0) {
            float dv = dinv[n];
            #pragma unroll
            for (int p2 = 0; p2 < 6; ++p2)
                Ah[(size_t)n * 32 + cg * 6 + p2] =
                    __halves2half2(__float2half_rn(acc[2 * p2] * dv),
                                   __float2half_rn(acc[2 * p2 + 1] * dv));
        } else {
            #pragma unroll
            for (int p2 = 0; p2 < 6; ++p2)
                Rh[(size_t)n * 24 + cg * 6 + p2] =
                    __halves2half2(__float2half_rn(acc[2 * p2]),
                                   __float2half_rn(acc[2 * p2 + 1]));
        }
    }
}

// ---------------- SpMM 48-wide: pair scheme, parity-contiguous chunk + b128 index reads ----------------

template <bool FUSEW>
__global__ void k_spmm48(const f16x2* __restrict__ Asrc,    // row stride 32 f16x2
                         const __half2* __restrict__ Rh,    // row stride 24 half2
                         const int* __restrict__ row_start, const int* __restrict__ deg,
                         const float* __restrict__ dinv, const int* __restrict__ csr,
                         const float* __restrict__ w1, __half2* __restrict__ Bout) {
    __shared__ float w1s[FUSEW ? KS * HID * HID : 1];
    __shared__ int chunk[4][64];
    if (FUSEW) {
        for (int i = threadIdx.x; i < KS * HID * HID; i += 256) w1s[i] = w1[i];
        __syncthreads();
    }
    int wv   = threadIdx.x >> 6;
    int node = (blockIdx.x * 256 + threadIdx.x) >> 6;   // one wave per node
    int lane = threadIdx.x & 63;
    int eo   = lane >> 5;           // edge parity within pair
    int cl   = lane & 31;           // col-pair index (cols 2cl, 2cl+1)
    int start = __builtin_amdgcn_readfirstlane(row_start[node]);
    int d     = __builtin_amdgcn_readfirstlane(deg[node]);
    int d4    = (d + 3) & ~3;       // csr padded with NN sentinels (zero row)
    float dv  = dinv[node];
    float2 r2 = make_float2(0.f, 0.f);
    if (cl < 24) r2 = __half22float2(Rh[(size_t)node * 24 + cl]);

    f16x2 h10 = {(_Float16)1.f, (_Float16)0.f};
    f16x2 h01 = {(_Float16)0.f, (_Float16)1.f};
    int* ch = &chunk[wv][0];
    const int* cp = ch + (eo << 5);               // parity's contiguous index run
    int spos = ((lane & 1) << 5) | (lane >> 1);   // stage edge `lane` at parity-contig pos
    float ax0 = 0.f, ay0 = 0.f, ax1 = 0.f, ay1 = 0.f;
    for (int b = 0; b < d4; b += 64) {
        int nb = min(64, d4 - b);               // multiple of 4
        if (lane < nb) ch[spos] = csr[start + b + lane];   // predicated: no CSR overfetch
        int npf = nb >> 1;                      // pairs (even)
        int p = 0;
        for (; p + 4 <= npf; p += 4) {
            int4 ci = *(const int4*)&cp[p];     // ds_read_b128: 4 edge indices
            f16x2 f0 = Asrc[(unsigned)ci.x * 32u + (unsigned)cl];
            f16x2 f1 = Asrc[(unsigned)ci.y * 32u + (unsigned)cl];
            f16x2 f2 = Asrc[(unsigned)ci.z * 32u + (unsigned)cl];
            f16x2 f3 = Asrc[(unsigned)ci.w * 32u + (unsigned)cl];
            ax0 = __builtin_amdgcn_fdot2(f0, h10, ax0, false);
            ay0 = __builtin_amdgcn_fdot2(f0, h01, ay0, false);
            ax1 = __builtin_amdgcn_fdot2(f1, h10, ax1, false);
            ay1 = __builtin_amdgcn_fdot2(f1, h01, ay1, false);
            ax0 = __builtin_amdgcn_fdot2(f2, h10, ax0, false);
            ay0 = __builtin_amdgcn_fdot2(f2, h01, ay0, false);
            ax1 = __builtin_amdgcn_fdot2(f3, h10, ax1, false);
            ay1 = __builtin_amdgcn_fdot2(f3, h01, ay1, false);
        }
        if (p < npf) {                           // remainder = 2 pairs (npf even)
            int2 ci = *(const int2*)&cp[p];      // ds_read_b64
            f16x2 f0 = Asrc[(unsigned)ci.x * 32u + (unsigned)cl];
            f16x2 f1 = Asrc[(unsigned)ci.y * 32u + (unsigned)cl];
            ax0 = __builtin_amdgcn_fdot2(f0, h10, ax0, false);
            ay0 = __builtin_amdgcn_fdot2(f0, h01, ay0, false);
            ax1 = __builtin_amdgcn_fdot2(f1, h10, ax1, false);
            ay1 = __builtin_amdgcn_fdot2(f1, h01, ay1, false);
        }
    }
    float ax = ax0 + ax1;
    float ay = ay0 + ay1;
    // combine edge parities
    ax += __shfl_xor(ax, 32, 64);
    ay += __shfl_xor(ay, 32, 64);
    // root + relu (both layer-1 propagates end in relu)
    float vx = fmaxf(ax * dv + r2.x, 0.f);
    float vy = fmaxf(ay * dv + r2.y, 0.f);

    if (FUSEW) {
        // out[k*16+p0], out[k*16+p0+1] = sum_h in[k*16+h] * w1[k][h][p]
        int k  = cl >> 3;              // (2cl)>>4
        int p0 = (2 * cl) & 15;
        float o0 = 0.f, o1 = 0.f;
        #pragma unroll
        for (int h2 = 0; h2 < 8; ++h2) {
            float ix = __shfl(vx, k * 8 + h2, 64);   // in[k*16 + 2h2]
            float iy = __shfl(vy, k * 8 + h2, 64);   // in[k*16 + 2h2+1]
            o0 += ix * w1s[k * 256 + (2 * h2) * 16 + p0]     + iy * w1s[k * 256 + (2 * h2 + 1) * 16 + p0];
            o1 += ix * w1s[k * 256 + (2 * h2) * 16 + p0 + 1] + iy * w1s[k * 256 + (2 * h2 + 1) * 16 + p0 + 1];
        }
        if (eo == 0 && cl < 24)
            Bout[(size_t)node * (PAD / 2) + cl] =
                __halves2half2(__float2half_rn(o0 * dv), __float2half_rn(o1 * dv));
    } else {
        if (eo == 0 && cl < 24)
            Bout[(size_t)node * (PAD / 2) + cl] =
                __halves2half2(__float2half_rn(vx), __float2half_rn(vy));
    }
}

// ---------------- fused mean+relu+transform2 ----------------

__global__ void k_mt2(const __half* __restrict__ L1, const float* __restrict__ iw,
                      const float* __restrict__ rw, const float* __restrict__ b2,
                      const float* __restrict__ dinv,
                      float* __restrict__ A2, float* __restrict__ R2) {
    __shared__ float wi[KS * HID * OUTC];
    __shared__ float wr_[KS * HID * OUTC];
    __shared__ float bb[KO];
    if (threadIdx.x < KS * HID * OUTC) { wi[threadIdx.x] = iw[threadIdx.x]; wr_[threadIdx.x] = rw[threadIdx.x]; }
    if (threadIdx.x < KO) bb[threadIdx.x] = b2[threadIdx.x];
    __syncthreads();
    int n = blockIdx.x * 256 + threadIdx.x;
    if (n >= NN) return;
    const __half2* hp = (const __half2*)(L1 + (size_t)n * PAD);
    float v[KH];
    #pragma unroll
    for (int q = 0; q < 24; ++q) {
        float2 f = __half22float2(hp[q]);
        v[q * 2 + 0] = f.x; v[q * 2 + 1] = f.y;
    }
    float h[HID];
    #pragma unroll
    for (int hh = 0; hh < HID; ++hh)
        h[hh] = fmaxf((v[hh] + v[16 + hh] + v[32 + hh]) * (1.f / 3.f), 0.f);
    float dv = dinv[n];
    #pragma unroll
    for (int k = 0; k < KS; ++k) {
        #pragma unroll
        for (int o = 0; o < OUTC; ++o) {
            float a = 0.f, r = bb[k * 2 + o];
            #pragma unroll
            for (int hh = 0; hh < HID; ++hh) {
                a += h[hh] * wi[k * 32 + hh * 2 + o];
                r += h[hh] * wr_[k * 32 + hh * 2 + o];
            }
            A2[n * KO + k * 2 + o] = a * dv;
            R2[n * KO + k * 2 + o] = r;
        }
    }
}

// ---------------- SpMM 6-wide #1: fused 2x2 gemm (w2), output pre-scaled ----------------

__global__ void k_spmm6_g(const float* __restrict__ Asrc, const float* __restrict__ R2,
                          const int* __restrict__ row_start, const int* __restrict__ deg,
                          const float* __restrict__ dinv, const int* __restrict__ csr,
                          const float* __restrict__ w2, float* __restrict__ Bout) {
    __shared__ float ws[KS * OUTC * OUTC];
    if (threadIdx.x < KS * OUTC * OUTC) ws[threadIdx.x] = w2[threadIdx.x];
    __syncthreads();
    int t = blockIdx.x * 256 + threadIdx.x;
    int node = t / KO, j = t % KO;
    bool active = node < NN;
    float acc = 0.f, r = 0.f, dv = 0.f;
    int start = 0, d = 0;
    if (active) {
        start = row_start[node];
        d     = deg[node];
        r     = R2[node * KO + j];
        dv    = dinv[node];
    }
    int e = 0;
    for (; e + 4 <= d; e += 4) {
        int c0 = csr[start + e + 0];
        int c1 = csr[start + e + 1];
        int c2 = csr[start + e + 2];
        int c3 = csr[start + e + 3];
        acc += Asrc[c0 * KO + j];
        acc += Asrc[c1 * KO + j];
        acc += Asrc[c2 * KO + j];
        acc += Asrc[c3 * KO + j];
    }
    for (; e < d; ++e)
        acc += Asrc[csr[start + e] * KO + j];
    float v = acc * dv + r;
    float other = __shfl_xor(v, 1, 64);
    if (active) {
        int k = j >> 1, p = j & 1;
        float v0 = (p == 0) ? v : other;
        float v1 = (p == 0) ? other : v;
        Bout[node * KO + j] = (v0 * ws[k * 4 + p] + v1 * ws[k * 4 + 2 + p]) * dv;
    }
}

// ---------------- SpMM 6-wide #2: fused mean + log_softmax (10 nodes/wave) ----------------

__global__ void k_spmm6_f(const float* __restrict__ Asrc, const float* __restrict__ R2,
                          const int* __restrict__ row_start, const int* __restrict__ deg,
                          const float* __restrict__ dinv, const int* __restrict__ csr,
                          float* __restrict__ out) {
    int wave = threadIdx.x >> 6;
    int l    = threadIdx.x & 63;
    int nl   = l / 6;            // 0..10 (10 = inactive)
    int j    = l - nl * 6;
    bool active = nl < 10;
    int node = blockIdx.x * 40 + wave * 10 + nl;
    float acc = 0.f, r = 0.f, dv = 0.f;
    int start = 0, d = 0;
    if (active) {
        start = row_start[node];
        d     = deg[node];
        r     = R2[node * KO + j];
        dv    = dinv[node];
    }
    int e = 0;
    for (; e + 4 <= d; e += 4) {
        int c0 = csr[start + e + 0];
        int c1 = csr[start + e + 1];
        int c2 = csr[start + e + 2];
        int c3 = csr[start + e + 3];
        acc += Asrc[c0 * KO + j];
        acc += Asrc[c1 * KO + j];
        acc += Asrc[c2 * KO + j];
        acc += Asrc[c3 * KO + j];
    }
    for (; e < d; ++e)
        acc += Asrc[csr[start + e] * KO + j];
    float v = acc * dv + r;
    int base = nl * 6;
    float o0 = (__shfl(v, base + 0, 64) + __shfl(v, base + 2, 64) + __shfl(v, base + 4, 64)) * (1.f / 3.f);
    float o1 = (__shfl(v, base + 1, 64) + __shfl(v, base + 3, 64) + __shfl(v, base + 5, 64)) * (1.f / 3.f);
    if (active && j == 0) {
        float m = fmaxf(o0, o1);
        float ls = m + logf(expf(o0 - m) + expf(o1 - m));
        *(float2*)(out + (size_t)node * 2) = make_float2(o0 - ls, o1 - ls);
    }
}

// ---------------- host ----------------

extern "C" void kernel_launch(void* const* d_in, const int* in_sizes, int n_in,
                              void* d_out, int out_size, void* d_ws, size_t ws_size,
                              hipStream_t stream) {
    const float* x   = (const float*)d_in[0];
    const int*   ei  = (const int*)d_in[1];
    const float* iw1 = (const float*)d_in[2];
    const float* w1  = (const float*)d_in[3];
    const float* rw1 = (const float*)d_in[4];
    const float* b1  = (const float*)d_in[5];
    const float* iw2 = (const float*)d_in[6];
    const float* w2  = (const float*)d_in[7];
    const float* rw2 = (const float*)d_in[8];
    const float* b2  = (const float*)d_in[9];
    const int* src = ei;
    const int* dst = ei + NE;
    float* out = (float*)d_out;

    char* ws = (char*)d_ws;
    size_t o = 0;
    int*     deg       = (int*)(ws + o);     o += (size_t)NN * 4;
    int*     row_start = (int*)(ws + o);     o += (size_t)NN * 4;
    float*   dinv      = (float*)(ws + o);   o += (size_t)NN * 4;
    int*     hist      = (int*)(ws + o);     o += (size_t)M1 * 4;
    int*     hist_scan = (int*)(ws + o);     o += (size_t)M1 * 4;
    int*     partials  = (int*)(ws + o);     o += 128 * 4;
    int*     csr       = (int*)(ws + o);     o += (size_t)CSR_CAP * 4;         // 14MB pad-4 CSR
    __half*  A         = (__half*)(ws + o);  o += (size_t)(NN + 1) * PAD * 2;  // 12.8MB
    __half2* Rh        = (__half2*)(ws + o); o += (size_t)NN * 24 * 4;         // 9.6MB fp16 R
    __half*  B         = (__half*)(ws + o);  o += (size_t)(NN + 1) * PAD * 2;  // 12.8MB
    float*   wT        = (float*)(ws + o);   o += 96 * 68 * 4;                 // 26KB transposed weights
    // overlays
    int*    recs  = (int*)A;                 // NE*4 = 12.8MB fits in A region; dead before t1
    __half* L1f   = A;                       // spmm48#2 output (reads B, not A)
    float*  A2    = (float*)Rh;              // layer-2 buffers live in Rh (dead after spmm48#2)
    float*  R2    = (float*)Rh + (size_t)NN * KO;
    float*  C2    = (float*)Rh + (size_t)NN * KO * 2;   // 7.2MB <= 9.6MB

    // ---- CSR build (5 dispatches) ----
    k_hist       <<<PB, 256, 0, stream>>>(dst, hist);
    k_partial    <<<NSCB, 256, 0, stream>>>(hist, partials, M1);
    k_downsweepF <<<NSCB, 256, 0, stream>>>(hist, partials, hist_scan, M1);
    k_pass2      <<<PB, 256, 0, stream>>>(src, dst, hist_scan, recs);
    k_degsort    <<<NBINS, 1024, 0, stream>>>(recs, hist_scan, deg, dinv, row_start, csr);

    // ---- layer 1 ----
    k_wprep <<<1, 256, 0, stream>>>(iw1, rw1, wT, (__half2*)A, (__half2*)B);
    k_t1    <<<dim3(T1B, 2), 256, 0, stream>>>(x, wT, b1, dinv, (__half2*)A, Rh);
    k_spmm48<true>  <<<NN / 4, 256, 0, stream>>>((const f16x2*)A, Rh, row_start, deg, dinv, csr, w1, (__half2*)B);
    k_spmm48<false> <<<NN / 4, 256, 0, stream>>>((const f16x2*)B, Rh, row_start, deg, dinv, csr, w1, (__half2*)L1f);

    // ---- layer 2 ----
    k_mt2     <<<(NN + 255) / 256, 256, 0, stream>>>(L1f, iw2, rw2, b2, dinv, A2, R2);
    k_spmm6_g <<<(NN * KO + 255) / 256, 256, 0, stream>>>(A2, R2, row_start, deg, dinv, csr, w2, C2);
    k_spmm6_f <<<NN / 40, 256, 0, stream>>>(C2, R2, row_start, deg, dinv, csr, out);
}